// Round 1
// baseline (2769.586 us; speedup 1.0000x reference)
//
#include <hip/hip_runtime.h>
#include <math.h>

#define IN_F 128
#define F1 256   // H1*C1
#define H1 2
#define F2 64
#define NEG 0.2f

// ---------------- GEMM1: x[N,128] @ W1[128,256] -> xh1[N,256] ----------------
// Epilogue: a_src1[n,h] = sum_c xh1[n,h*128+c]*att_src1[h,c]  (flat: att[c], h=c>>7)
__global__ __launch_bounds__(256) void gemm1_fused(
    const float* __restrict__ x, const float* __restrict__ W1,
    const float* __restrict__ att_s, const float* __restrict__ att_d,
    float* __restrict__ xh1, float* __restrict__ a_src, float* __restrict__ a_dst, int N)
{
    __shared__ float xs[4][IN_F];
    __shared__ float pss[4][4], psd[4][4]; // [wave][row]
    int t = threadIdx.x;
    int n0 = blockIdx.x * 4;
    for (int j = 0; j < 2; ++j) {
        int idx = t + j * 256;
        int r = idx >> 7, col = idx & 127;
        int row = n0 + r; if (row >= N) row = N - 1;
        xs[r][col] = x[(long)row * IN_F + col];
    }
    __syncthreads();
    int c = t;
    float as_w = att_s[c], ad_w = att_d[c];
    float acc0 = 0, acc1 = 0, acc2 = 0, acc3 = 0;
    #pragma unroll 4
    for (int k = 0; k < IN_F; ++k) {
        float w = W1[k * F1 + c];
        acc0 = fmaf(xs[0][k], w, acc0);
        acc1 = fmaf(xs[1][k], w, acc1);
        acc2 = fmaf(xs[2][k], w, acc2);
        acc3 = fmaf(xs[3][k], w, acc3);
    }
    float accs[4] = {acc0, acc1, acc2, acc3};
    int wave = t >> 6, lane = t & 63;
    #pragma unroll
    for (int r = 0; r < 4; ++r) {
        if (n0 + r < N) xh1[(long)(n0 + r) * F1 + c] = accs[r];
        float vs = accs[r] * as_w;
        float vd = accs[r] * ad_w;
        for (int o = 32; o > 0; o >>= 1) {
            vs += __shfl_xor(vs, o);
            vd += __shfl_xor(vd, o);
        }
        if (lane == 0) { pss[wave][r] = vs; psd[wave][r] = vd; }
    }
    __syncthreads();
    if (t < 8) {
        int h = t & 1, r = t >> 1;
        if (n0 + r < N) {
            a_src[(long)(n0 + r) * H1 + h] = pss[2 * h][r] + pss[2 * h + 1][r];
            a_dst[(long)(n0 + r) * H1 + h] = psd[2 * h][r] + psd[2 * h + 1][r];
        }
    }
}

// ---------------- GEMM2: relu(z1+b1)[N,256] @ W2[256,64] -> xh2[N,64] --------
__global__ __launch_bounds__(256) void gemm2_fused(
    const float* __restrict__ z1, const float* __restrict__ b1,
    const float* __restrict__ W2,
    const float* __restrict__ att_s, const float* __restrict__ att_d,
    float* __restrict__ xh2, float* __restrict__ a_src, float* __restrict__ a_dst, int N)
{
    __shared__ float zs[4][F1];
    int t = threadIdx.x;
    int n0 = blockIdx.x * 4;
    for (int j = 0; j < 4; ++j) {
        int idx = t + j * 256;
        int r = idx >> 8, col = idx & 255;
        int row = n0 + r; if (row >= N) row = N - 1;
        float v = z1[(long)row * F1 + col] + b1[col];
        zs[r][col] = fmaxf(v, 0.f);
    }
    __syncthreads();
    int r = t >> 6, c = t & 63;
    float acc = 0;
    #pragma unroll 8
    for (int k = 0; k < F1; ++k)
        acc = fmaf(zs[r][k], W2[k * F2 + c], acc);
    if (n0 + r < N) xh2[(long)(n0 + r) * F2 + c] = acc;
    float vs = acc * att_s[c];
    float vd = acc * att_d[c];
    for (int o = 32; o > 0; o >>= 1) { vs += __shfl_xor(vs, o); vd += __shfl_xor(vd, o); }
    if (c == 0 && n0 + r < N) { a_src[n0 + r] = vs; a_dst[n0 + r] = vd; }
}

// ---------------- edge softmax (unnormalized exp + denom accumulation) -------
template<int H>
__global__ void edge_soft(const int* __restrict__ ei_s, const int* __restrict__ ei_d,
                          const float* __restrict__ a_s, const float* __restrict__ a_d,
                          float* __restrict__ ex, float* __restrict__ denom, int E, int Ep)
{
    int i = blockIdx.x * blockDim.x + threadIdx.x;
    if (i >= Ep) return;
    int s = (i < E) ? ei_s[i] : (i - E);
    int d = (i < E) ? ei_d[i] : (i - E);
    #pragma unroll
    for (int h = 0; h < H; ++h) {
        float e = a_s[(long)s * H + h] + a_d[(long)d * H + h];
        e = (e > 0.f) ? e : NEG * e;
        float v = expf(e);
        ex[(long)i * H + h] = v;
        atomicAdd(&denom[(long)d * H + h], v);
    }
}

// ---------------- aggregation layer 1: wave per edge, 256 channels -----------
__global__ __launch_bounds__(256) void aggregate1(
    const int* __restrict__ ei_s, const int* __restrict__ ei_d,
    const float* __restrict__ xh1, const float* __restrict__ ex,
    const float* __restrict__ denom, float* __restrict__ out, int E, int Ep)
{
    int wave = threadIdx.x >> 6, lane = threadIdx.x & 63;
    long i = (long)blockIdx.x * 4 + wave;
    if (i >= Ep) return;
    int s = (i < E) ? ei_s[i] : (int)(i - E);
    int d = (i < E) ? ei_d[i] : (int)(i - E);
    int h = lane >> 5;
    float alpha = ex[i * H1 + h] / (denom[(long)d * H1 + h] + 1e-16f);
    const float4* xv = (const float4*)(xh1 + (long)s * F1);
    float4 v = xv[lane];
    float* op = out + (long)d * F1 + lane * 4;
    atomicAdd(op + 0, alpha * v.x);
    atomicAdd(op + 1, alpha * v.y);
    atomicAdd(op + 2, alpha * v.z);
    atomicAdd(op + 3, alpha * v.w);
}

// ---------------- aggregation layer 2: wave per edge, 64 channels ------------
__global__ __launch_bounds__(256) void aggregate2(
    const int* __restrict__ ei_s, const int* __restrict__ ei_d,
    const float* __restrict__ xh2, const float* __restrict__ ex,
    const float* __restrict__ denom, float* __restrict__ out, int E, int Ep)
{
    int wave = threadIdx.x >> 6, lane = threadIdx.x & 63;
    long i = (long)blockIdx.x * 4 + wave;
    if (i >= Ep) return;
    int s = (i < E) ? ei_s[i] : (int)(i - E);
    int d = (i < E) ? ei_d[i] : (int)(i - E);
    float alpha = ex[i] / (denom[d] + 1e-16f);
    float v = xh2[(long)s * F2 + lane];
    atomicAdd(out + (long)d * F2 + lane, alpha * v);
}

// ---------------- decode: dot(z2[a], z2[b]) over original edges --------------
__global__ __launch_bounds__(256) void decode_k(
    const int* __restrict__ e0, const int* __restrict__ e1,
    const float* __restrict__ z2, const float* __restrict__ b2,
    float* __restrict__ out, int E)
{
    int wave = threadIdx.x >> 6, lane = threadIdx.x & 63;
    long e = (long)blockIdx.x * 4 + wave;
    if (e >= E) return;
    int a = e0[e], b = e1[e];
    float va = z2[(long)a * F2 + lane] + b2[lane];
    float vb = z2[(long)b * F2 + lane] + b2[lane];
    float p = va * vb;
    for (int o = 32; o > 0; o >>= 1) p += __shfl_xor(p, o);
    if (lane == 0) out[e] = p;
}

extern "C" void kernel_launch(void* const* d_in, const int* in_sizes, int n_in,
                              void* d_out, int out_size, void* d_ws, size_t ws_size,
                              hipStream_t stream) {
    const float* x   = (const float*)d_in[0];
    const int*   ei  = (const int*)d_in[1];
    const float* W1  = (const float*)d_in[2];
    const float* as1 = (const float*)d_in[3];
    const float* ad1 = (const float*)d_in[4];
    const float* b1  = (const float*)d_in[5];
    const float* W2  = (const float*)d_in[6];
    const float* as2 = (const float*)d_in[7];
    const float* ad2 = (const float*)d_in[8];
    const float* b2  = (const float*)d_in[9];

    int N  = in_sizes[0] / IN_F;   // 50000
    int E  = in_sizes[1] / 2;      // 600000
    int Ep = E + N;                // with self loops
    const int* ei_src = ei;
    const int* ei_dst = ei + E;

    float* ws = (float*)d_ws;
    size_t off = 0;
    auto alloc = [&](size_t n) { float* p = ws + off; off += (n + 63) & ~(size_t)63; return p; };

    float* xh1    = alloc((size_t)N * F1);
    float* a_src1 = alloc((size_t)N * H1);
    float* a_dst1 = alloc((size_t)N * H1);
    float* ex1    = alloc((size_t)Ep * H1);
    float* xh2    = alloc((size_t)N * F2);
    float* a_src2 = alloc(N);
    float* a_dst2 = alloc(N);
    float* ex2    = alloc(Ep);
    // contiguous zero-init region
    float* zero_base = ws + off;
    float* z1     = alloc((size_t)N * F1);
    float* denom1 = alloc((size_t)N * H1);
    float* out2   = alloc((size_t)N * F2);
    float* denom2 = alloc(N);
    size_t zero_bytes = (size_t)((ws + off) - zero_base) * sizeof(float);
    hipMemsetAsync(zero_base, 0, zero_bytes, stream);

    gemm1_fused<<<(N + 3) / 4, 256, 0, stream>>>(x, W1, as1, ad1, xh1, a_src1, a_dst1, N);
    edge_soft<H1><<<(Ep + 255) / 256, 256, 0, stream>>>(ei_src, ei_dst, a_src1, a_dst1, ex1, denom1, E, Ep);
    aggregate1<<<(Ep + 3) / 4, 256, 0, stream>>>(ei_src, ei_dst, xh1, ex1, denom1, z1, E, Ep);
    gemm2_fused<<<(N + 3) / 4, 256, 0, stream>>>(z1, b1, W2, as2, ad2, xh2, a_src2, a_dst2, N);
    edge_soft<1><<<(Ep + 255) / 256, 256, 0, stream>>>(ei_src, ei_dst, a_src2, a_dst2, ex2, denom2, E, Ep);
    aggregate2<<<(Ep + 3) / 4, 256, 0, stream>>>(ei_src, ei_dst, xh2, ex2, denom2, out2, E, Ep);
    decode_k<<<(E + 3) / 4, 256, 0, stream>>>(ei_src, ei_dst, out2, b2, (float*)d_out, E);
}

// Round 3
// 610.209 us; speedup vs baseline: 4.5388x; 4.5388x over previous
//
#include <hip/hip_runtime.h>
#include <math.h>

#define IN_F 128
#define F1 256   // H1*C1
#define H1 2
#define F2 64
#define NEG 0.2f

// ---------------- GEMM1: x[N,128] @ W1[128,256] -> xh1[N,256] ----------------
__global__ __launch_bounds__(256) void gemm1_fused(
    const float* __restrict__ x, const float* __restrict__ W1,
    const float* __restrict__ att_s, const float* __restrict__ att_d,
    float* __restrict__ xh1, float* __restrict__ a_src, float* __restrict__ a_dst, int N)
{
    __shared__ float xs[4][IN_F];
    __shared__ float pss[4][4], psd[4][4]; // [wave][row]
    int t = threadIdx.x;
    int n0 = blockIdx.x * 4;
    for (int j = 0; j < 2; ++j) {
        int idx = t + j * 256;
        int r = idx >> 7, col = idx & 127;
        int row = n0 + r; if (row >= N) row = N - 1;
        xs[r][col] = x[(long)row * IN_F + col];
    }
    __syncthreads();
    int c = t;
    float as_w = att_s[c], ad_w = att_d[c];
    float acc0 = 0, acc1 = 0, acc2 = 0, acc3 = 0;
    #pragma unroll 4
    for (int k = 0; k < IN_F; ++k) {
        float w = W1[k * F1 + c];
        acc0 = fmaf(xs[0][k], w, acc0);
        acc1 = fmaf(xs[1][k], w, acc1);
        acc2 = fmaf(xs[2][k], w, acc2);
        acc3 = fmaf(xs[3][k], w, acc3);
    }
    float accs[4] = {acc0, acc1, acc2, acc3};
    int wave = t >> 6, lane = t & 63;
    #pragma unroll
    for (int r = 0; r < 4; ++r) {
        if (n0 + r < N) xh1[(long)(n0 + r) * F1 + c] = accs[r];
        float vs = accs[r] * as_w;
        float vd = accs[r] * ad_w;
        for (int o = 32; o > 0; o >>= 1) {
            vs += __shfl_xor(vs, o);
            vd += __shfl_xor(vd, o);
        }
        if (lane == 0) { pss[wave][r] = vs; psd[wave][r] = vd; }
    }
    __syncthreads();
    if (t < 8) {
        int h = t & 1, r = t >> 1;
        if (n0 + r < N) {
            a_src[(long)(n0 + r) * H1 + h] = pss[2 * h][r] + pss[2 * h + 1][r];
            a_dst[(long)(n0 + r) * H1 + h] = psd[2 * h][r] + psd[2 * h + 1][r];
        }
    }
}

// ---------------- GEMM2: relu(z1+b1)[N,256] @ W2[256,64] -> xh2[N,64] --------
__global__ __launch_bounds__(256) void gemm2_fused(
    const float* __restrict__ z1, const float* __restrict__ b1,
    const float* __restrict__ W2,
    const float* __restrict__ att_s, const float* __restrict__ att_d,
    float* __restrict__ xh2, float* __restrict__ a_src, float* __restrict__ a_dst, int N)
{
    __shared__ float zs[4][F1];
    int t = threadIdx.x;
    int n0 = blockIdx.x * 4;
    for (int j = 0; j < 4; ++j) {
        int idx = t + j * 256;
        int r = idx >> 8, col = idx & 255;
        int row = n0 + r; if (row >= N) row = N - 1;
        float v = z1[(long)row * F1 + col] + b1[col];
        zs[r][col] = fmaxf(v, 0.f);
    }
    __syncthreads();
    int r = t >> 6, c = t & 63;
    float acc = 0;
    #pragma unroll 8
    for (int k = 0; k < F1; ++k)
        acc = fmaf(zs[r][k], W2[k * F2 + c], acc);
    if (n0 + r < N) xh2[(long)(n0 + r) * F2 + c] = acc;
    float vs = acc * att_s[c];
    float vd = acc * att_d[c];
    for (int o = 32; o > 0; o >>= 1) { vs += __shfl_xor(vs, o); vd += __shfl_xor(vd, o); }
    if (c == 0 && n0 + r < N) { a_src[n0 + r] = vs; a_dst[n0 + r] = vd; }
}

// ---------------- CSR build: histogram -> scan -> scatter --------------------
__global__ void hist_k(const int* __restrict__ ei_d, int* __restrict__ deg, int E, int Ep)
{
    int i = blockIdx.x * blockDim.x + threadIdx.x;
    if (i >= Ep) return;
    int d = (i < E) ? ei_d[i] : (i - E);
    atomicAdd(&deg[d], 1);
}

// single-block exclusive scan over N entries; rowptr[N] = total
__global__ __launch_bounds__(1024) void scan_k(const int* __restrict__ deg,
                                               int* __restrict__ rowptr, int N)
{
    __shared__ int wsum[16];
    __shared__ int carry_sh;
    int t = threadIdx.x, lane = t & 63, w = t >> 6;
    if (t == 0) carry_sh = 0;
    __syncthreads();
    for (int base = 0; base < N; base += 1024) {
        int v = (base + t < N) ? deg[base + t] : 0;
        int incl = v;
        #pragma unroll
        for (int o = 1; o < 64; o <<= 1) {
            int nb = __shfl_up(incl, o);
            if (lane >= o) incl += nb;
        }
        if (lane == 63) wsum[w] = incl;
        __syncthreads();
        if (w == 0 && lane < 16) {
            int x = wsum[lane];
            #pragma unroll
            for (int o = 1; o < 16; o <<= 1) {
                int nb = __shfl_up(x, o);
                if (lane >= o) x += nb;
            }
            wsum[lane] = x; // inclusive over waves
        }
        __syncthreads();
        int carry = carry_sh;
        int woff = (w == 0) ? 0 : wsum[w - 1];
        if (base + t < N) rowptr[base + t] = carry + woff + incl - v;
        int total = wsum[15];
        __syncthreads();
        if (t == 0) carry_sh = carry + total;
        __syncthreads();
    }
    if (t == 0) rowptr[N] = carry_sh;
}

__global__ void scatter_k(const int* __restrict__ ei_s, const int* __restrict__ ei_d,
                          const int* __restrict__ rowptr, int* __restrict__ cursor,
                          int* __restrict__ csr_src, int E, int Ep)
{
    int i = blockIdx.x * blockDim.x + threadIdx.x;
    if (i >= Ep) return;
    int s = (i < E) ? ei_s[i] : (i - E);
    int d = (i < E) ? ei_d[i] : (i - E);
    int pos = atomicAdd(&cursor[d], 1);
    csr_src[rowptr[d] + pos] = s;
}

// ------- layer-1 aggregation: one wave per dst node, fused softmax ----------
// 32-edge chunks: lanes 0-31 hold head-0 exp, lanes 32-63 head-1 exp for the
// SAME 32 edges. All shuffles execute at full 64-lane convergence (divergent
// shuffle on gfx950 reads undefined data from inactive source lanes).
__global__ __launch_bounds__(256) void agg1_csr(
    const int* __restrict__ rowptr, const int* __restrict__ csr_src,
    const float* __restrict__ a_s, const float* __restrict__ a_d,  // [N,2]
    const float* __restrict__ xh1, float* __restrict__ z1, int N)
{
    int wave = threadIdx.x >> 6, lane = threadIdx.x & 63;
    int d = blockIdx.x * 4 + wave;
    if (d >= N) return;
    int row = rowptr[d], end = rowptr[d + 1];
    int h = lane >> 5;       // head this lane's channels belong to (lane*4 .. lane*4+3)
    int l5 = lane & 31;
    float adh = a_d[(long)d * 2 + h];
    float4 acc = {0.f, 0.f, 0.f, 0.f};
    float den = 0.f;         // lanes 0-31: head0 partials; 32-63: head1 partials
    for (int base = row; base < end; base += 32) {
        int cnt = min(32, end - base);
        int sreg = 0; float e = 0.f;
        if (l5 < cnt) {
            sreg = csr_src[base + l5];
            float v = a_s[(long)sreg * 2 + h] + adh;
            v = (v > 0.f) ? v : NEG * v;
            e = expf(v);
            den += e;
        }
        for (int j = 0; j < cnt; ++j) {
            int s = __shfl(sreg, j);            // lane j holds src of edge base+j
            float w = __shfl(e, j + (h << 5));  // head-matched exp of edge base+j
            float4 vv = ((const float4*)(xh1 + (long)s * F1))[lane];
            acc.x = fmaf(w, vv.x, acc.x);
            acc.y = fmaf(w, vv.y, acc.y);
            acc.z = fmaf(w, vv.z, acc.z);
            acc.w = fmaf(w, vv.w, acc.w);
        }
    }
    // reduce den within each 32-lane half (offsets < 32 stay in-half)
    for (int o = 16; o > 0; o >>= 1) den += __shfl_xor(den, o);
    float inv = 1.0f / (den + 1e-16f);
    float4 o4 = {acc.x * inv, acc.y * inv, acc.z * inv, acc.w * inv};
    ((float4*)(z1 + (long)d * F1))[lane] = o4;
}

// ------- layer-2 aggregation: one wave per dst node, 64 channels ------------
__global__ __launch_bounds__(256) void agg2_csr(
    const int* __restrict__ rowptr, const int* __restrict__ csr_src,
    const float* __restrict__ a_s, const float* __restrict__ a_d,  // [N]
    const float* __restrict__ xh2, float* __restrict__ out2, int N)
{
    int wave = threadIdx.x >> 6, lane = threadIdx.x & 63;
    int d = blockIdx.x * 4 + wave;
    if (d >= N) return;
    int row = rowptr[d], end = rowptr[d + 1];
    float adv = a_d[d];
    float acc = 0.f, den = 0.f;
    for (int base = row; base < end; base += 64) {
        int cnt = min(64, end - base);
        float ev = 0.f; int sreg = 0;
        if (lane < cnt) {
            sreg = csr_src[base + lane];
            float v = a_s[sreg] + adv; v = (v > 0.f) ? v : NEG * v;
            ev = expf(v);
            den += ev;
        }
        for (int j = 0; j < cnt; ++j) {
            int s = __shfl(sreg, j);
            float w = __shfl(ev, j);
            acc = fmaf(w, xh2[(long)s * F2 + lane], acc);
        }
    }
    for (int o = 32; o > 0; o >>= 1) den += __shfl_xor(den, o);
    out2[(long)d * F2 + lane] = acc / (den + 1e-16f);
}

// ---------------- decode: dot(z2[a], z2[b]) over original edges --------------
__global__ __launch_bounds__(256) void decode_k(
    const int* __restrict__ e0, const int* __restrict__ e1,
    const float* __restrict__ z2, const float* __restrict__ b2,
    float* __restrict__ out, int E)
{
    int wave = threadIdx.x >> 6, lane = threadIdx.x & 63;
    long e = (long)blockIdx.x * 4 + wave;
    if (e >= E) return;
    int a = e0[e], b = e1[e];
    float va = z2[(long)a * F2 + lane] + b2[lane];
    float vb = z2[(long)b * F2 + lane] + b2[lane];
    float p = va * vb;
    for (int o = 32; o > 0; o >>= 1) p += __shfl_xor(p, o);
    if (lane == 0) out[e] = p;
}

extern "C" void kernel_launch(void* const* d_in, const int* in_sizes, int n_in,
                              void* d_out, int out_size, void* d_ws, size_t ws_size,
                              hipStream_t stream) {
    const float* x   = (const float*)d_in[0];
    const int*   ei  = (const int*)d_in[1];
    const float* W1  = (const float*)d_in[2];
    const float* as1 = (const float*)d_in[3];
    const float* ad1 = (const float*)d_in[4];
    const float* b1  = (const float*)d_in[5];
    const float* W2  = (const float*)d_in[6];
    const float* as2 = (const float*)d_in[7];
    const float* ad2 = (const float*)d_in[8];
    const float* b2  = (const float*)d_in[9];

    int N  = in_sizes[0] / IN_F;   // 50000
    int E  = in_sizes[1] / 2;      // 600000
    int Ep = E + N;                // with self loops
    const int* ei_src = ei;
    const int* ei_dst = ei + E;

    float* ws = (float*)d_ws;
    size_t off = 0;
    auto alloc = [&](size_t n) { float* p = ws + off; off += (n + 63) & ~(size_t)63; return p; };

    float* xh1    = alloc((size_t)N * F1);
    float* a_src1 = alloc((size_t)N * H1);
    float* a_dst1 = alloc((size_t)N * H1);
    float* xh2    = alloc((size_t)N * F2);
    float* a_src2 = alloc(N);
    float* a_dst2 = alloc(N);
    float* z1     = alloc((size_t)N * F1);
    float* out2   = alloc((size_t)N * F2);
    int* rowptr   = (int*)alloc(N + 64);
    int* csr_src  = (int*)alloc(Ep);
    // zero-init region: deg + cursor
    int* deg      = (int*)alloc(N);
    int* cursor   = (int*)alloc(N);
    hipMemsetAsync(deg, 0, ((size_t)(cursor + N) - (size_t)deg), stream);

    // CSR build
    hist_k<<<(Ep + 255) / 256, 256, 0, stream>>>(ei_dst, deg, E, Ep);
    scan_k<<<1, 1024, 0, stream>>>(deg, rowptr, N);
    scatter_k<<<(Ep + 255) / 256, 256, 0, stream>>>(ei_src, ei_dst, rowptr, cursor, csr_src, E, Ep);

    // layer 1
    gemm1_fused<<<(N + 3) / 4, 256, 0, stream>>>(x, W1, as1, ad1, xh1, a_src1, a_dst1, N);
    agg1_csr<<<(N + 3) / 4, 256, 0, stream>>>(rowptr, csr_src, a_src1, a_dst1, xh1, z1, N);

    // layer 2
    gemm2_fused<<<(N + 3) / 4, 256, 0, stream>>>(z1, b1, W2, as2, ad2, xh2, a_src2, a_dst2, N);
    agg2_csr<<<(N + 3) / 4, 256, 0, stream>>>(rowptr, csr_src, a_src2, a_dst2, xh2, out2, N);

    // decode
    decode_k<<<(E + 3) / 4, 256, 0, stream>>>(ei_src, ei_dst, out2, b2, (float*)d_out, E);
}

// Round 4
// 525.241 us; speedup vs baseline: 5.2730x; 1.1618x over previous
//
#include <hip/hip_runtime.h>
#include <math.h>

#define IN_F 128
#define F1 256   // H1*C1
#define H1 2
#define F2 64
#define NEG 0.2f

// ---------------- tiled fp32 GEMM: C[M,NTOT] = act(A[M,KTOT]) @ W[KTOT,NTOT] -
// 64x64 tile / block(256), 4x4 regs/thread, K staged in 64-chunks (32 KB LDS).
// RELU: apply max(a+bias,0) to A during staging (gemm2 input).
// ATT_EP: fused epilogue computing a_src/a_dst row dots (requires NTOT==64).
template<int KTOT, int NTOT, bool RELU, bool ATT_EP>
__global__ __launch_bounds__(256) void gemm_tiled(
    const float* __restrict__ A, const float* __restrict__ bias,
    const float* __restrict__ W, float* __restrict__ C,
    const float* __restrict__ att_s, const float* __restrict__ att_d,
    float* __restrict__ a_src, float* __restrict__ a_dst, int M)
{
    __shared__ float As[64][64];  // [k][row]
    __shared__ float Ws[64][64];  // [k][col]
    int t = threadIdx.x;
    int tx = t & 15, ty = t >> 4;
    int m0 = blockIdx.x * 64;
    int n0 = blockIdx.y * 64;
    float acc[4][4];
    #pragma unroll
    for (int i = 0; i < 4; ++i)
        #pragma unroll
        for (int j = 0; j < 4; ++j) acc[i][j] = 0.f;

    for (int kc = 0; kc < KTOT; kc += 64) {
        // stage A (transposed): As[k][r] = act(A[m0+r][kc+k])
        {
            int r = t & 63;
            int row = m0 + r; if (row >= M) row = M - 1;
            const float* arow = A + (long)row * KTOT + kc + (t >> 6) * 4;
            #pragma unroll
            for (int p = 0; p < 4; ++p) {
                int kk = (t >> 6) * 4 + p * 16;
                float4 v = *(const float4*)(arow + p * 16);
                if (RELU) {
                    float4 bb = *(const float4*)&bias[kc + kk];
                    v.x = fmaxf(v.x + bb.x, 0.f);
                    v.y = fmaxf(v.y + bb.y, 0.f);
                    v.z = fmaxf(v.z + bb.z, 0.f);
                    v.w = fmaxf(v.w + bb.w, 0.f);
                }
                As[kk + 0][r] = v.x;
                As[kk + 1][r] = v.y;
                As[kk + 2][r] = v.z;
                As[kk + 3][r] = v.w;
            }
        }
        // stage W: Ws[k][c] = W[kc+k][n0+c]
        #pragma unroll
        for (int p = 0; p < 4; ++p) {
            int k = p * 16 + (t >> 4);
            int cq = t & 15;
            *(float4*)&Ws[k][cq * 4] =
                *(const float4*)&W[(long)(kc + k) * NTOT + n0 + cq * 4];
        }
        __syncthreads();
        #pragma unroll 8
        for (int k = 0; k < 64; ++k) {
            float4 a4 = *(const float4*)&As[k][ty * 4];
            float4 w4 = *(const float4*)&Ws[k][tx * 4];
            float av[4] = {a4.x, a4.y, a4.z, a4.w};
            float wv[4] = {w4.x, w4.y, w4.z, w4.w};
            #pragma unroll
            for (int i = 0; i < 4; ++i)
                #pragma unroll
                for (int j = 0; j < 4; ++j)
                    acc[i][j] = fmaf(av[i], wv[j], acc[i][j]);
        }
        __syncthreads();
    }
    // store
    #pragma unroll
    for (int i = 0; i < 4; ++i) {
        int row = m0 + ty * 4 + i;
        if (row < M) {
            float4 o4 = {acc[i][0], acc[i][1], acc[i][2], acc[i][3]};
            *(float4*)&C[(long)row * NTOT + n0 + tx * 4] = o4;
        }
    }
    if (ATT_EP) {
        // per-row dot with att vectors (NTOT==64: block holds full rows)
        float4 as4 = *(const float4*)&att_s[tx * 4];
        float4 ad4 = *(const float4*)&att_d[tx * 4];
        #pragma unroll
        for (int i = 0; i < 4; ++i) {
            float ps = acc[i][0] * as4.x + acc[i][1] * as4.y +
                       acc[i][2] * as4.z + acc[i][3] * as4.w;
            float pd = acc[i][0] * ad4.x + acc[i][1] * ad4.y +
                       acc[i][2] * ad4.z + acc[i][3] * ad4.w;
            #pragma unroll
            for (int o = 1; o < 16; o <<= 1) {
                ps += __shfl_xor(ps, o);
                pd += __shfl_xor(pd, o);
            }
            int row = m0 + ty * 4 + i;
            if (tx == 0 && row < M) { a_src[row] = ps; a_dst[row] = pd; }
        }
    }
}

// ---------------- layer-1 attention dots: a[n,h] = sum_c xh1[n,hc]*att[h,c] --
__global__ __launch_bounds__(256) void att1_k(
    const float* __restrict__ xh1, const float* __restrict__ att_s,
    const float* __restrict__ att_d, float* __restrict__ a_src,
    float* __restrict__ a_dst, int N)
{
    int wave = threadIdx.x >> 6, lane = threadIdx.x & 63;
    int n = blockIdx.x * 4 + wave;
    if (n >= N) return;
    float4 xv = ((const float4*)(xh1 + (long)n * F1))[lane];
    float4 sv = ((const float4*)att_s)[lane];
    float4 dv = ((const float4*)att_d)[lane];
    float ps = xv.x * sv.x + xv.y * sv.y + xv.z * sv.z + xv.w * sv.w;
    float pd = xv.x * dv.x + xv.y * dv.y + xv.z * dv.z + xv.w * dv.w;
    #pragma unroll
    for (int o = 16; o > 0; o >>= 1) { ps += __shfl_xor(ps, o); pd += __shfl_xor(pd, o); }
    int h = lane >> 5;
    if ((lane & 31) == 0) {
        a_src[(long)n * 2 + h] = ps;
        a_dst[(long)n * 2 + h] = pd;
    }
}

// ---------------- CSR build: histogram -> scan -> scatter --------------------
__global__ void hist_k(const int* __restrict__ ei_d, int* __restrict__ deg, int E, int Ep)
{
    int i = blockIdx.x * blockDim.x + threadIdx.x;
    if (i >= Ep) return;
    int d = (i < E) ? ei_d[i] : (i - E);
    atomicAdd(&deg[d], 1);
}

// single-block exclusive scan over N entries; rowptr[N] = total
__global__ __launch_bounds__(1024) void scan_k(const int* __restrict__ deg,
                                               int* __restrict__ rowptr, int N)
{
    __shared__ int wsum[16];
    __shared__ int carry_sh;
    int t = threadIdx.x, lane = t & 63, w = t >> 6;
    if (t == 0) carry_sh = 0;
    __syncthreads();
    for (int base = 0; base < N; base += 1024) {
        int v = (base + t < N) ? deg[base + t] : 0;
        int incl = v;
        #pragma unroll
        for (int o = 1; o < 64; o <<= 1) {
            int nb = __shfl_up(incl, o);
            if (lane >= o) incl += nb;
        }
        if (lane == 63) wsum[w] = incl;
        __syncthreads();
        if (w == 0 && lane < 16) {
            int x = wsum[lane];
            #pragma unroll
            for (int o = 1; o < 16; o <<= 1) {
                int nb = __shfl_up(x, o);
                if (lane >= o) x += nb;
            }
            wsum[lane] = x; // inclusive over waves
        }
        __syncthreads();
        int carry = carry_sh;
        int woff = (w == 0) ? 0 : wsum[w - 1];
        if (base + t < N) rowptr[base + t] = carry + woff + incl - v;
        int total = wsum[15];
        __syncthreads();
        if (t == 0) carry_sh = carry + total;
        __syncthreads();
    }
    if (t == 0) rowptr[N] = carry_sh;
}

__global__ void scatter_k(const int* __restrict__ ei_s, const int* __restrict__ ei_d,
                          const int* __restrict__ rowptr, int* __restrict__ cursor,
                          int* __restrict__ csr_src, int E, int Ep)
{
    int i = blockIdx.x * blockDim.x + threadIdx.x;
    if (i >= Ep) return;
    int s = (i < E) ? ei_s[i] : (i - E);
    int d = (i < E) ? ei_d[i] : (i - E);
    int pos = atomicAdd(&cursor[d], 1);
    csr_src[rowptr[d] + pos] = s;
}

// ------- layer-1 aggregation: one wave per dst node, fused softmax ----------
// 32-edge chunks: lanes 0-31 hold head-0 exp, lanes 32-63 head-1 exp for the
// SAME 32 edges; all shuffles fully convergent.
__global__ __launch_bounds__(256) void agg1_csr(
    const int* __restrict__ rowptr, const int* __restrict__ csr_src,
    const float* __restrict__ a_s, const float* __restrict__ a_d,  // [N,2]
    const float* __restrict__ xh1, float* __restrict__ z1, int N)
{
    int wave = threadIdx.x >> 6, lane = threadIdx.x & 63;
    int d = blockIdx.x * 4 + wave;
    if (d >= N) return;
    int row = rowptr[d], end = rowptr[d + 1];
    int h = lane >> 5;
    int l5 = lane & 31;
    float adh = a_d[(long)d * 2 + h];
    float4 acc = {0.f, 0.f, 0.f, 0.f};
    float den = 0.f;
    for (int base = row; base < end; base += 32) {
        int cnt = min(32, end - base);
        int sreg = 0; float e = 0.f;
        if (l5 < cnt) {
            sreg = csr_src[base + l5];
            float v = a_s[(long)sreg * 2 + h] + adh;
            v = (v > 0.f) ? v : NEG * v;
            e = expf(v);
            den += e;
        }
        for (int j = 0; j < cnt; ++j) {
            int s = __shfl(sreg, j);
            float w = __shfl(e, j + (h << 5));
            float4 vv = ((const float4*)(xh1 + (long)s * F1))[lane];
            acc.x = fmaf(w, vv.x, acc.x);
            acc.y = fmaf(w, vv.y, acc.y);
            acc.z = fmaf(w, vv.z, acc.z);
            acc.w = fmaf(w, vv.w, acc.w);
        }
    }
    for (int o = 16; o > 0; o >>= 1) den += __shfl_xor(den, o);
    float inv = 1.0f / (den + 1e-16f);
    float4 o4 = {acc.x * inv, acc.y * inv, acc.z * inv, acc.w * inv};
    ((float4*)(z1 + (long)d * F1))[lane] = o4;
}

// ------- layer-2 aggregation: one wave per dst node, 64 channels ------------
__global__ __launch_bounds__(256) void agg2_csr(
    const int* __restrict__ rowptr, const int* __restrict__ csr_src,
    const float* __restrict__ a_s, const float* __restrict__ a_d,  // [N]
    const float* __restrict__ xh2, float* __restrict__ out2, int N)
{
    int wave = threadIdx.x >> 6, lane = threadIdx.x & 63;
    int d = blockIdx.x * 4 + wave;
    if (d >= N) return;
    int row = rowptr[d], end = rowptr[d + 1];
    float adv = a_d[d];
    float acc = 0.f, den = 0.f;
    for (int base = row; base < end; base += 64) {
        int cnt = min(64, end - base);
        float ev = 0.f; int sreg = 0;
        if (lane < cnt) {
            sreg = csr_src[base + lane];
            float v = a_s[sreg] + adv; v = (v > 0.f) ? v : NEG * v;
            ev = expf(v);
            den += ev;
        }
        for (int j = 0; j < cnt; ++j) {
            int s = __shfl(sreg, j);
            float w = __shfl(ev, j);
            acc = fmaf(w, xh2[(long)s * F2 + lane], acc);
        }
    }
    for (int o = 32; o > 0; o >>= 1) den += __shfl_xor(den, o);
    out2[(long)d * F2 + lane] = acc / (den + 1e-16f);
}

// ---------------- decode: dot(z2[a], z2[b]) over original edges --------------
__global__ __launch_bounds__(256) void decode_k(
    const int* __restrict__ e0, const int* __restrict__ e1,
    const float* __restrict__ z2, const float* __restrict__ b2,
    float* __restrict__ out, int E)
{
    int wave = threadIdx.x >> 6, lane = threadIdx.x & 63;
    long e = (long)blockIdx.x * 4 + wave;
    if (e >= E) return;
    int a = e0[e], b = e1[e];
    float va = z2[(long)a * F2 + lane] + b2[lane];
    float vb = z2[(long)b * F2 + lane] + b2[lane];
    float p = va * vb;
    for (int o = 32; o > 0; o >>= 1) p += __shfl_xor(p, o);
    if (lane == 0) out[e] = p;
}

extern "C" void kernel_launch(void* const* d_in, const int* in_sizes, int n_in,
                              void* d_out, int out_size, void* d_ws, size_t ws_size,
                              hipStream_t stream) {
    const float* x   = (const float*)d_in[0];
    const int*   ei  = (const int*)d_in[1];
    const float* W1  = (const float*)d_in[2];
    const float* as1 = (const float*)d_in[3];
    const float* ad1 = (const float*)d_in[4];
    const float* b1  = (const float*)d_in[5];
    const float* W2  = (const float*)d_in[6];
    const float* as2 = (const float*)d_in[7];
    const float* ad2 = (const float*)d_in[8];
    const float* b2  = (const float*)d_in[9];

    int N  = in_sizes[0] / IN_F;   // 50000
    int E  = in_sizes[1] / 2;      // 600000
    int Ep = E + N;                // with self loops
    const int* ei_src = ei;
    const int* ei_dst = ei + E;

    float* ws = (float*)d_ws;
    size_t off = 0;
    auto alloc = [&](size_t n) { float* p = ws + off; off += (n + 63) & ~(size_t)63; return p; };

    float* xh1    = alloc((size_t)N * F1);
    float* a_src1 = alloc((size_t)N * H1);
    float* a_dst1 = alloc((size_t)N * H1);
    float* xh2    = alloc((size_t)N * F2);
    float* a_src2 = alloc(N);
    float* a_dst2 = alloc(N);
    float* z1     = alloc((size_t)N * F1);
    float* out2   = alloc((size_t)N * F2);
    int* rowptr   = (int*)alloc(N + 64);
    int* csr_src  = (int*)alloc(Ep);
    // zero-init region: deg + cursor
    int* deg      = (int*)alloc(N);
    int* cursor   = (int*)alloc(N);
    hipMemsetAsync(deg, 0, ((size_t)(cursor + N) - (size_t)deg), stream);

    // CSR build
    hist_k<<<(Ep + 255) / 256, 256, 0, stream>>>(ei_dst, deg, E, Ep);
    scan_k<<<1, 1024, 0, stream>>>(deg, rowptr, N);
    scatter_k<<<(Ep + 255) / 256, 256, 0, stream>>>(ei_src, ei_dst, rowptr, cursor, csr_src, E, Ep);

    int mt = (N + 63) / 64;
    // layer 1
    gemm_tiled<IN_F, F1, false, false><<<dim3(mt, F1 / 64), 256, 0, stream>>>(
        x, nullptr, W1, xh1, nullptr, nullptr, nullptr, nullptr, N);
    att1_k<<<(N + 3) / 4, 256, 0, stream>>>(xh1, as1, ad1, a_src1, a_dst1, N);
    agg1_csr<<<(N + 3) / 4, 256, 0, stream>>>(rowptr, csr_src, a_src1, a_dst1, xh1, z1, N);

    // layer 2 (relu+bias fused into staging, att dots fused into epilogue)
    gemm_tiled<F1, F2, true, true><<<dim3(mt, 1), 256, 0, stream>>>(
        z1, b1, W2, xh2, as2, ad2, a_src2, a_dst2, N);
    agg2_csr<<<(N + 3) / 4, 256, 0, stream>>>(rowptr, csr_src, a_src2, a_dst2, xh2, out2, N);

    // decode
    decode_k<<<(E + 3) / 4, 256, 0, stream>>>(ei_src, ei_dst, out2, b2, (float*)d_out, E);
}

// Round 5
// 413.682 us; speedup vs baseline: 6.6950x; 1.2697x over previous
//
#include <hip/hip_runtime.h>
#include <math.h>

#define IN_F 128
#define F1 256   // H1*C1
#define H1 2
#define F2 64
#define NEG 0.2f

// ---------------- tiled fp32 GEMM -------------------------------------------
// C[M rows] tile 64x64 per block(256), 4x4 regs/thread, K staged in 64-chunks.
// LDA/LDW/LDC: row strides. HEADOFF: A column offset = (blockIdx.y>>1)*KTOT
// (layer-1 per-head GEMM from G[N,2,128]). RELU: stage act(A+bias).
// ATT_EP: fused a_src/a_dst row-dot epilogue (requires single col-tile, LDC=64).
template<int KTOT, int LDA, int LDW, int LDC, bool RELU, bool ATT_EP, bool HEADOFF>
__global__ __launch_bounds__(256) void gemm_tiled(
    const float* __restrict__ A, const float* __restrict__ bias,
    const float* __restrict__ W, float* __restrict__ C,
    const float* __restrict__ att_s, const float* __restrict__ att_d,
    float* __restrict__ a_src, float* __restrict__ a_dst, int M)
{
    __shared__ float As[64][64];  // [k][row]
    __shared__ float Ws[64][64];  // [k][col]
    int t = threadIdx.x;
    int tx = t & 15, ty = t >> 4;
    int m0 = blockIdx.x * 64;
    int n0 = blockIdx.y * 64;
    long aoff = HEADOFF ? (long)(blockIdx.y >> 1) * KTOT : 0;
    float acc[4][4];
    #pragma unroll
    for (int i = 0; i < 4; ++i)
        #pragma unroll
        for (int j = 0; j < 4; ++j) acc[i][j] = 0.f;

    for (int kc = 0; kc < KTOT; kc += 64) {
        {
            int r = t & 63;
            int row = m0 + r; if (row >= M) row = M - 1;
            const float* arow = A + (long)row * LDA + aoff + kc + (t >> 6) * 4;
            #pragma unroll
            for (int p = 0; p < 4; ++p) {
                int kk = (t >> 6) * 4 + p * 16;
                float4 v = *(const float4*)(arow + p * 16);
                if (RELU) {
                    float4 bb = *(const float4*)&bias[kc + kk];
                    v.x = fmaxf(v.x + bb.x, 0.f);
                    v.y = fmaxf(v.y + bb.y, 0.f);
                    v.z = fmaxf(v.z + bb.z, 0.f);
                    v.w = fmaxf(v.w + bb.w, 0.f);
                }
                As[kk + 0][r] = v.x;
                As[kk + 1][r] = v.y;
                As[kk + 2][r] = v.z;
                As[kk + 3][r] = v.w;
            }
        }
        #pragma unroll
        for (int p = 0; p < 4; ++p) {
            int k = p * 16 + (t >> 4);
            int cq = t & 15;
            *(float4*)&Ws[k][cq * 4] =
                *(const float4*)&W[(long)(kc + k) * LDW + n0 + cq * 4];
        }
        __syncthreads();
        #pragma unroll 8
        for (int k = 0; k < 64; ++k) {
            float4 a4 = *(const float4*)&As[k][ty * 4];
            float4 w4 = *(const float4*)&Ws[k][tx * 4];
            float av[4] = {a4.x, a4.y, a4.z, a4.w};
            float wv[4] = {w4.x, w4.y, w4.z, w4.w};
            #pragma unroll
            for (int i = 0; i < 4; ++i)
                #pragma unroll
                for (int j = 0; j < 4; ++j)
                    acc[i][j] = fmaf(av[i], wv[j], acc[i][j]);
        }
        __syncthreads();
    }
    #pragma unroll
    for (int i = 0; i < 4; ++i) {
        int row = m0 + ty * 4 + i;
        if (row < M) {
            float4 o4 = {acc[i][0], acc[i][1], acc[i][2], acc[i][3]};
            *(float4*)&C[(long)row * LDC + n0 + tx * 4] = o4;
        }
    }
    if (ATT_EP) {
        float4 as4 = *(const float4*)&att_s[tx * 4];
        float4 ad4 = *(const float4*)&att_d[tx * 4];
        #pragma unroll
        for (int i = 0; i < 4; ++i) {
            float ps = acc[i][0] * as4.x + acc[i][1] * as4.y +
                       acc[i][2] * as4.z + acc[i][3] * as4.w;
            float pd = acc[i][0] * ad4.x + acc[i][1] * ad4.y +
                       acc[i][2] * ad4.z + acc[i][3] * ad4.w;
            #pragma unroll
            for (int o = 1; o < 16; o <<= 1) {
                ps += __shfl_xor(ps, o);
                pd += __shfl_xor(pd, o);
            }
            int row = m0 + ty * 4 + i;
            if (tx == 0 && row < M) { a_src[row] = ps; a_dst[row] = pd; }
        }
    }
}

// ------- UV precompute: UV4[k] = {U[k,0],U[k,1],V[k,0],V[k,1]} ---------------
// U[k,h] = sum_c W1[k, h*128+c]*att_s[h*128+c]; V likewise with att_d.
__global__ void uv_k(const float* __restrict__ W1, const float* __restrict__ as1,
                     const float* __restrict__ ad1, float* __restrict__ UV4)
{
    int t = threadIdx.x;           // 256 threads: k = t>>1, h = t&1
    int k = t >> 1, h = t & 1;
    const float* wrow = W1 + (long)k * F1 + h * 128;
    const float* sa = as1 + h * 128;
    const float* da = ad1 + h * 128;
    float u = 0.f, v = 0.f;
    for (int c = 0; c < 128; ++c) {
        float w = wrow[c];
        u = fmaf(w, sa[c], u);
        v = fmaf(w, da[c], v);
    }
    UV4[k * 4 + h] = u;
    UV4[k * 4 + 2 + h] = v;
}

// ------- layer-1 attention scalars: a_src1/a_dst1[n,h] = x[n]·U/V[:,h] -------
__global__ __launch_bounds__(256) void att1v_k(
    const float* __restrict__ x, const float* __restrict__ UV4,
    float* __restrict__ a_src, float* __restrict__ a_dst, int N)
{
    int wave = threadIdx.x >> 6, lane = threadIdx.x & 63;
    int n = blockIdx.x * 4 + wave;
    if (n >= N) return;
    float2 xv = ((const float2*)(x + (long)n * IN_F))[lane];
    float4 u0 = ((const float4*)UV4)[2 * lane];
    float4 u1 = ((const float4*)UV4)[2 * lane + 1];
    float p0 = xv.x * u0.x + xv.y * u1.x;  // a_src head0
    float p1 = xv.x * u0.y + xv.y * u1.y;  // a_src head1
    float p2 = xv.x * u0.z + xv.y * u1.z;  // a_dst head0
    float p3 = xv.x * u0.w + xv.y * u1.w;  // a_dst head1
    #pragma unroll
    for (int o = 32; o > 0; o >>= 1) {
        p0 += __shfl_xor(p0, o); p1 += __shfl_xor(p1, o);
        p2 += __shfl_xor(p2, o); p3 += __shfl_xor(p3, o);
    }
    if (lane == 0) {
        a_src[(long)n * 2 + 0] = p0; a_src[(long)n * 2 + 1] = p1;
        a_dst[(long)n * 2 + 0] = p2; a_dst[(long)n * 2 + 1] = p3;
    }
}

// ---------------- CSR build: histogram -> scan -> scatter --------------------
__global__ void hist_k(const int* __restrict__ ei_d, int* __restrict__ deg, int E, int Ep)
{
    int i = blockIdx.x * blockDim.x + threadIdx.x;
    if (i >= Ep) return;
    int d = (i < E) ? ei_d[i] : (i - E);
    atomicAdd(&deg[d], 1);
}

__global__ __launch_bounds__(1024) void scan_k(const int* __restrict__ deg,
                                               int* __restrict__ rowptr, int N)
{
    __shared__ int wsum[16];
    __shared__ int carry_sh;
    int t = threadIdx.x, lane = t & 63, w = t >> 6;
    if (t == 0) carry_sh = 0;
    __syncthreads();
    for (int base = 0; base < N; base += 1024) {
        int v = (base + t < N) ? deg[base + t] : 0;
        int incl = v;
        #pragma unroll
        for (int o = 1; o < 64; o <<= 1) {
            int nb = __shfl_up(incl, o);
            if (lane >= o) incl += nb;
        }
        if (lane == 63) wsum[w] = incl;
        __syncthreads();
        if (w == 0 && lane < 16) {
            int x = wsum[lane];
            #pragma unroll
            for (int o = 1; o < 16; o <<= 1) {
                int nb = __shfl_up(x, o);
                if (lane >= o) x += nb;
            }
            wsum[lane] = x;
        }
        __syncthreads();
        int carry = carry_sh;
        int woff = (w == 0) ? 0 : wsum[w - 1];
        if (base + t < N) rowptr[base + t] = carry + woff + incl - v;
        int total = wsum[15];
        __syncthreads();
        if (t == 0) carry_sh = carry + total;
        __syncthreads();
    }
    if (t == 0) rowptr[N] = carry_sh;
}

__global__ void scatter_k(const int* __restrict__ ei_s, const int* __restrict__ ei_d,
                          const int* __restrict__ rowptr, int* __restrict__ cursor,
                          int* __restrict__ csr_src, int E, int Ep)
{
    int i = blockIdx.x * blockDim.x + threadIdx.x;
    if (i >= Ep) return;
    int s = (i < E) ? ei_s[i] : (i - E);
    int d = (i < E) ? ei_d[i] : (i - E);
    int pos = atomicAdd(&cursor[d], 1);
    csr_src[rowptr[d] + pos] = s;
}

// ------- layer-1 aggregation in INPUT space: G[d,h,:] = sum alpha^h_e x[src] -
// 32-edge chunks; lanes 0-31 exp head0, lanes 32-63 exp head1 (same edges).
// j-loop: 2 edges in flight; group g=lane>>5 handles edge 2j+g with float4
// loads of x (32 lanes cover 128 ch), accumulating BOTH heads (8 fma / 16 B).
__global__ __launch_bounds__(256) void agg1x(
    const int* __restrict__ rowptr, const int* __restrict__ csr_src,
    const float* __restrict__ a_s, const float* __restrict__ a_d,  // [N,2]
    const float* __restrict__ x, float* __restrict__ G, int N)
{
    int wave = threadIdx.x >> 6, lane = threadIdx.x & 63;
    int d = blockIdx.x * 4 + wave;
    if (d >= N) return;
    int row = rowptr[d], end = rowptr[d + 1];
    int h = lane >> 5, l5 = lane & 31;
    float adh = a_d[(long)d * 2 + h];
    float a0[4] = {0,0,0,0}, a1[4] = {0,0,0,0};
    float den = 0.f;
    for (int base = row; base < end; base += 32) {
        int cnt = min(32, end - base);
        int sreg = 0; float e = 0.f;
        if (l5 < cnt) {
            sreg = csr_src[base + l5];
            float v = a_s[(long)sreg * 2 + h] + adh;
            v = (v > 0.f) ? v : NEG * v;
            e = expf(v);
            den += e;
        }
        int jmax = (cnt + 1) >> 1;
        for (int j = 0; j < jmax; ++j) {
            int m = 2 * j + h;                    // group g == h handles edge m
            int s = __shfl(sreg, m);              // overflow m: sreg=0, w=0 -> safe
            float w0 = __shfl(e, m);
            float w1 = __shfl(e, 32 | m);
            float4 v = *(const float4*)(x + (long)s * IN_F + l5 * 4);
            a0[0] = fmaf(w0, v.x, a0[0]); a0[1] = fmaf(w0, v.y, a0[1]);
            a0[2] = fmaf(w0, v.z, a0[2]); a0[3] = fmaf(w0, v.w, a0[3]);
            a1[0] = fmaf(w1, v.x, a1[0]); a1[1] = fmaf(w1, v.y, a1[1]);
            a1[2] = fmaf(w1, v.z, a1[2]); a1[3] = fmaf(w1, v.w, a1[3]);
        }
    }
    // den: reduce within each 32-lane half
    #pragma unroll
    for (int o = 16; o > 0; o >>= 1) den += __shfl_xor(den, o);
    // cross-group combine (each group summed edges of one parity)
    #pragma unroll
    for (int p = 0; p < 4; ++p) {
        a0[p] += __shfl_xor(a0[p], 32);
        a1[p] += __shfl_xor(a1[p], 32);
    }
    float inv = 1.0f / (den + 1e-16f);
    float* acch = (h == 0) ? a0 : a1;   // half h writes head h
    float4 o4 = {acch[0] * inv, acch[1] * inv, acch[2] * inv, acch[3] * inv};
    *(float4*)(G + (long)d * F1 + h * 128 + l5 * 4) = o4;
}

// ------- layer-2 aggregation: 4 edges in flight, float4 loads ---------------
// Fuses +b2 into the output (out2b = aggregated + bias) for decode.
__global__ __launch_bounds__(256) void agg2_csr(
    const int* __restrict__ rowptr, const int* __restrict__ csr_src,
    const float* __restrict__ a_s, const float* __restrict__ a_d,  // [N]
    const float* __restrict__ xh2, const float* __restrict__ b2,
    float* __restrict__ out2b, int N)
{
    int wave = threadIdx.x >> 6, lane = threadIdx.x & 63;
    int d = blockIdx.x * 4 + wave;
    if (d >= N) return;
    int row = rowptr[d], end = rowptr[d + 1];
    float adv = a_d[d];
    int g = lane >> 4, q = lane & 15;
    float acc[4] = {0,0,0,0};
    float den = 0.f;
    for (int base = row; base < end; base += 64) {
        int cnt = min(64, end - base);
        float ev = 0.f; int sreg = 0;
        if (lane < cnt) {
            sreg = csr_src[base + lane];
            float v = a_s[sreg] + adv; v = (v > 0.f) ? v : NEG * v;
            ev = expf(v);
            den += ev;
        }
        int jmax = (cnt + 3) >> 2;
        for (int j = 0; j < jmax; ++j) {
            int m = 4 * j + g;
            int s = __shfl(sreg, m);              // overflow m: w=0 -> safe
            float w = __shfl(ev, m);
            float4 v = *(const float4*)(xh2 + (long)s * F2 + q * 4);
            acc[0] = fmaf(w, v.x, acc[0]); acc[1] = fmaf(w, v.y, acc[1]);
            acc[2] = fmaf(w, v.z, acc[2]); acc[3] = fmaf(w, v.w, acc[3]);
        }
    }
    #pragma unroll
    for (int o = 32; o > 0; o >>= 1) den += __shfl_xor(den, o);
    #pragma unroll
    for (int p = 0; p < 4; ++p) {
        acc[p] += __shfl_xor(acc[p], 16);
        acc[p] += __shfl_xor(acc[p], 32);
    }
    if (g == 0) {
        float inv = 1.0f / (den + 1e-16f);
        float4 bb = *(const float4*)&b2[q * 4];
        float4 o4 = {acc[0] * inv + bb.x, acc[1] * inv + bb.y,
                     acc[2] * inv + bb.z, acc[3] * inv + bb.w};
        *(float4*)(out2b + (long)d * F2 + q * 4) = o4;
    }
}

// ---------------- decode: 16 lanes/edge, float4 loads ------------------------
__global__ __launch_bounds__(256) void decode_k(
    const int* __restrict__ e0, const int* __restrict__ e1,
    const float* __restrict__ z2b, float* __restrict__ out, int E)
{
    int q = threadIdx.x & 15;
    long e = (long)blockIdx.x * 16 + (threadIdx.x >> 4);
    if (e >= E) return;
    int a = e0[e], b = e1[e];
    float4 va = *(const float4*)(z2b + (long)a * F2 + q * 4);
    float4 vb = *(const float4*)(z2b + (long)b * F2 + q * 4);
    float p = va.x * vb.x + va.y * vb.y + va.z * vb.z + va.w * vb.w;
    #pragma unroll
    for (int o = 1; o < 16; o <<= 1) p += __shfl_xor(p, o);
    if (q == 0) out[e] = p;
}

extern "C" void kernel_launch(void* const* d_in, const int* in_sizes, int n_in,
                              void* d_out, int out_size, void* d_ws, size_t ws_size,
                              hipStream_t stream) {
    const float* x   = (const float*)d_in[0];
    const int*   ei  = (const int*)d_in[1];
    const float* W1  = (const float*)d_in[2];
    const float* as1 = (const float*)d_in[3];
    const float* ad1 = (const float*)d_in[4];
    const float* b1  = (const float*)d_in[5];
    const float* W2  = (const float*)d_in[6];
    const float* as2 = (const float*)d_in[7];
    const float* ad2 = (const float*)d_in[8];
    const float* b2  = (const float*)d_in[9];

    int N  = in_sizes[0] / IN_F;   // 50000
    int E  = in_sizes[1] / 2;      // 600000
    int Ep = E + N;
    const int* ei_src = ei;
    const int* ei_dst = ei + E;

    float* ws = (float*)d_ws;
    size_t off = 0;
    auto alloc = [&](size_t n) { float* p = ws + off; off += (n + 63) & ~(size_t)63; return p; };

    float* G      = alloc((size_t)N * F1);
    float* z1     = alloc((size_t)N * F1);
    float* xh2    = alloc((size_t)N * F2);
    float* out2b  = alloc((size_t)N * F2);
    float* a_src1 = alloc((size_t)N * H1);
    float* a_dst1 = alloc((size_t)N * H1);
    float* a_src2 = alloc(N);
    float* a_dst2 = alloc(N);
    float* UV4    = alloc(IN_F * 4);
    int* rowptr   = (int*)alloc(N + 64);
    int* csr_src  = (int*)alloc(Ep);
    int* deg      = (int*)alloc(N);
    int* cursor   = (int*)alloc(N);
    hipMemsetAsync(deg, 0, ((size_t)(cursor + N) - (size_t)deg), stream);

    // CSR build
    hist_k<<<(Ep + 255) / 256, 256, 0, stream>>>(ei_dst, deg, E, Ep);
    scan_k<<<1, 1024, 0, stream>>>(deg, rowptr, N);
    scatter_k<<<(Ep + 255) / 256, 256, 0, stream>>>(ei_src, ei_dst, rowptr, cursor, csr_src, E, Ep);

    int mt = (N + 63) / 64;
    // layer 1: attention scalars from x directly, aggregate x, then GEMM
    uv_k<<<1, 256, 0, stream>>>(W1, as1, ad1, UV4);
    att1v_k<<<(N + 3) / 4, 256, 0, stream>>>(x, UV4, a_src1, a_dst1, N);
    agg1x<<<(N + 3) / 4, 256, 0, stream>>>(rowptr, csr_src, a_src1, a_dst1, x, G, N);
    // z1[:, y*64..] = G[:, h*128..] @ W1[:, y*64..], h = y>>1
    gemm_tiled<IN_F, F1, F1, F1, false, false, true><<<dim3(mt, 4), 256, 0, stream>>>(
        G, nullptr, W1, z1, nullptr, nullptr, nullptr, nullptr, N);

    // layer 2
    gemm_tiled<F1, F1, F2, F2, true, true, false><<<dim3(mt, 1), 256, 0, stream>>>(
        z1, b1, W2, xh2, as2, ad2, a_src2, a_dst2, N);
    agg2_csr<<<(N + 3) / 4, 256, 0, stream>>>(rowptr, csr_src, a_src2, a_dst2, xh2, b2, out2b, N);

    // decode
    decode_k<<<(E + 15) / 16, 256, 0, stream>>>(ei_src, ei_dst, out2b, (float*)d_out, E);
}

// Round 6
// 407.998 us; speedup vs baseline: 6.7882x; 1.0139x over previous
//
#include <hip/hip_runtime.h>
#include <math.h>

#define IN_F 128
#define F1 256   // H1*C1
#define H1 2
#define F2 64
#define NEG 0.2f

// ---------------- tiled fp32 GEMM: 128x64 tile, 8x4 regs/thread --------------
// block(256): tx=t&15 (4 cols each), ty=t>>4 (8 rows each). K staged 64-chunks.
// As[64][128] (32KB) + Ws[64][64] (16KB) = 48KB -> 3 blocks/CU.
// LDA/LDW/LDC: row strides. HEADOFF: A col offset = (n0>>7)*KTOT (layer-1
// per-head GEMM). RELU: stage act(A+bias). ATT_EP: fused a_src/a_dst row dots
// (requires single col-tile, LDC==64).
template<int KTOT, int LDA, int LDW, int LDC, bool RELU, bool ATT_EP, bool HEADOFF>
__global__ __launch_bounds__(256) void gemm_tiled(
    const float* __restrict__ A, const float* __restrict__ bias,
    const float* __restrict__ W, float* __restrict__ C,
    const float* __restrict__ att_s, const float* __restrict__ att_d,
    float* __restrict__ a_src, float* __restrict__ a_dst, int M)
{
    __shared__ float As[64][128];  // [k][row]
    __shared__ float Ws[64][64];   // [k][col]
    int t = threadIdx.x;
    int tx = t & 15, ty = t >> 4;
    int m0 = blockIdx.x * 128;
    int n0 = blockIdx.y * 64;
    long aoff = HEADOFF ? (long)(blockIdx.y >> 1) * KTOT : 0;
    float acc[8][4];
    #pragma unroll
    for (int i = 0; i < 8; ++i)
        #pragma unroll
        for (int j = 0; j < 4; ++j) acc[i][j] = 0.f;

    for (int kc = 0; kc < KTOT; kc += 64) {
        // stage A transposed: As[k][r] = act(A[m0+r][aoff+kc+k])
        {
            int r = t & 127;
            int row = m0 + r; if (row >= M) row = M - 1;
            const float* arow = A + (long)row * LDA + aoff + kc;
            #pragma unroll
            for (int p = 0; p < 8; ++p) {
                int kk = ((t >> 7) + 2 * p) * 4;
                float4 v = *(const float4*)(arow + kk);
                if (RELU) {
                    float4 bb = *(const float4*)&bias[kc + kk];
                    v.x = fmaxf(v.x + bb.x, 0.f);
                    v.y = fmaxf(v.y + bb.y, 0.f);
                    v.z = fmaxf(v.z + bb.z, 0.f);
                    v.w = fmaxf(v.w + bb.w, 0.f);
                }
                As[kk + 0][r] = v.x;
                As[kk + 1][r] = v.y;
                As[kk + 2][r] = v.z;
                As[kk + 3][r] = v.w;
            }
        }
        // stage W: Ws[k][c] = W[kc+k][n0+c]
        #pragma unroll
        for (int p = 0; p < 4; ++p) {
            int k = p * 16 + (t >> 4);
            int cq = t & 15;
            *(float4*)&Ws[k][cq * 4] =
                *(const float4*)&W[(long)(kc + k) * LDW + n0 + cq * 4];
        }
        __syncthreads();
        #pragma unroll 4
        for (int k = 0; k < 64; ++k) {
            float4 a04 = *(const float4*)&As[k][ty * 8];
            float4 a14 = *(const float4*)&As[k][ty * 8 + 4];
            float4 w4  = *(const float4*)&Ws[k][tx * 4];
            float av[8] = {a04.x, a04.y, a04.z, a04.w, a14.x, a14.y, a14.z, a14.w};
            float wv[4] = {w4.x, w4.y, w4.z, w4.w};
            #pragma unroll
            for (int i = 0; i < 8; ++i)
                #pragma unroll
                for (int j = 0; j < 4; ++j)
                    acc[i][j] = fmaf(av[i], wv[j], acc[i][j]);
        }
        __syncthreads();
    }
    #pragma unroll
    for (int i = 0; i < 8; ++i) {
        int row = m0 + ty * 8 + i;
        if (row < M) {
            float4 o4 = {acc[i][0], acc[i][1], acc[i][2], acc[i][3]};
            *(float4*)&C[(long)row * LDC + n0 + tx * 4] = o4;
        }
    }
    if (ATT_EP) {
        float4 as4 = *(const float4*)&att_s[tx * 4];
        float4 ad4 = *(const float4*)&att_d[tx * 4];
        #pragma unroll
        for (int i = 0; i < 8; ++i) {
            float ps = acc[i][0] * as4.x + acc[i][1] * as4.y +
                       acc[i][2] * as4.z + acc[i][3] * as4.w;
            float pd = acc[i][0] * ad4.x + acc[i][1] * ad4.y +
                       acc[i][2] * ad4.z + acc[i][3] * ad4.w;
            #pragma unroll
            for (int o = 1; o < 16; o <<= 1) {
                ps += __shfl_xor(ps, o);
                pd += __shfl_xor(pd, o);
            }
            int row = m0 + ty * 8 + i;
            if (tx == 0 && row < M) { a_src[row] = ps; a_dst[row] = pd; }
        }
    }
}

// ------- UV precompute: UV4[k] = {U[k,0],U[k,1],V[k,0],V[k,1]} ---------------
__global__ void uv_k(const float* __restrict__ W1, const float* __restrict__ as1,
                     const float* __restrict__ ad1, float* __restrict__ UV4)
{
    int t = threadIdx.x;           // 256 threads: k = t>>1, h = t&1
    int k = t >> 1, h = t & 1;
    const float* wrow = W1 + (long)k * F1 + h * 128;
    const float* sa = as1 + h * 128;
    const float* da = ad1 + h * 128;
    float u = 0.f, v = 0.f;
    for (int c = 0; c < 128; ++c) {
        float w = wrow[c];
        u = fmaf(w, sa[c], u);
        v = fmaf(w, da[c], v);
    }
    UV4[k * 4 + h] = u;
    UV4[k * 4 + 2 + h] = v;
}

// ------- layer-1 attention scalars: a_src1/a_dst1[n,h] = x[n]·U/V[:,h] -------
__global__ __launch_bounds__(256) void att1v_k(
    const float* __restrict__ x, const float* __restrict__ UV4,
    float* __restrict__ a_src, float* __restrict__ a_dst, int N)
{
    int wave = threadIdx.x >> 6, lane = threadIdx.x & 63;
    int n = blockIdx.x * 4 + wave;
    if (n >= N) return;
    float2 xv = ((const float2*)(x + (long)n * IN_F))[lane];
    float4 u0 = ((const float4*)UV4)[2 * lane];
    float4 u1 = ((const float4*)UV4)[2 * lane + 1];
    float p0 = xv.x * u0.x + xv.y * u1.x;
    float p1 = xv.x * u0.y + xv.y * u1.y;
    float p2 = xv.x * u0.z + xv.y * u1.z;
    float p3 = xv.x * u0.w + xv.y * u1.w;
    #pragma unroll
    for (int o = 32; o > 0; o >>= 1) {
        p0 += __shfl_xor(p0, o); p1 += __shfl_xor(p1, o);
        p2 += __shfl_xor(p2, o); p3 += __shfl_xor(p3, o);
    }
    if (lane == 0) {
        a_src[(long)n * 2 + 0] = p0; a_src[(long)n * 2 + 1] = p1;
        a_dst[(long)n * 2 + 0] = p2; a_dst[(long)n * 2 + 1] = p3;
    }
}

// ---------------- CSR build: histogram -> scan -> scatter --------------------
__global__ void hist_k(const int* __restrict__ ei_d, int* __restrict__ deg, int E, int Ep)
{
    int i = blockIdx.x * blockDim.x + threadIdx.x;
    if (i >= Ep) return;
    int d = (i < E) ? ei_d[i] : (i - E);
    atomicAdd(&deg[d], 1);
}

__global__ __launch_bounds__(1024) void scan_k(const int* __restrict__ deg,
                                               int* __restrict__ rowptr, int N)
{
    __shared__ int wsum[16];
    __shared__ int carry_sh;
    int t = threadIdx.x, lane = t & 63, w = t >> 6;
    if (t == 0) carry_sh = 0;
    __syncthreads();
    for (int base = 0; base < N; base += 1024) {
        int v = (base + t < N) ? deg[base + t] : 0;
        int incl = v;
        #pragma unroll
        for (int o = 1; o < 64; o <<= 1) {
            int nb = __shfl_up(incl, o);
            if (lane >= o) incl += nb;
        }
        if (lane == 63) wsum[w] = incl;
        __syncthreads();
        if (w == 0 && lane < 16) {
            int x = wsum[lane];
            #pragma unroll
            for (int o = 1; o < 16; o <<= 1) {
                int nb = __shfl_up(x, o);
                if (lane >= o) x += nb;
            }
            wsum[lane] = x;
        }
        __syncthreads();
        int carry = carry_sh;
        int woff = (w == 0) ? 0 : wsum[w - 1];
        if (base + t < N) rowptr[base + t] = carry + woff + incl - v;
        int total = wsum[15];
        __syncthreads();
        if (t == 0) carry_sh = carry + total;
        __syncthreads();
    }
    if (t == 0) rowptr[N] = carry_sh;
}

__global__ void scatter_k(const int* __restrict__ ei_s, const int* __restrict__ ei_d,
                          const int* __restrict__ rowptr, int* __restrict__ cursor,
                          int* __restrict__ csr_src, int E, int Ep)
{
    int i = blockIdx.x * blockDim.x + threadIdx.x;
    if (i >= Ep) return;
    int s = (i < E) ? ei_s[i] : (i - E);
    int d = (i < E) ? ei_d[i] : (i - E);
    int pos = atomicAdd(&cursor[d], 1);
    csr_src[rowptr[d] + pos] = s;
}

// ------- layer-1 aggregation in INPUT space: G[d,h,:] = sum alpha^h_e x[src] -
__global__ __launch_bounds__(256) void agg1x(
    const int* __restrict__ rowptr, const int* __restrict__ csr_src,
    const float* __restrict__ a_s, const float* __restrict__ a_d,  // [N,2]
    const float* __restrict__ x, float* __restrict__ G, int N)
{
    int wave = threadIdx.x >> 6, lane = threadIdx.x & 63;
    int d = blockIdx.x * 4 + wave;
    if (d >= N) return;
    int row = rowptr[d], end = rowptr[d + 1];
    int h = lane >> 5, l5 = lane & 31;
    float adh = a_d[(long)d * 2 + h];
    float a0[4] = {0,0,0,0}, a1[4] = {0,0,0,0};
    float den = 0.f;
    for (int base = row; base < end; base += 32) {
        int cnt = min(32, end - base);
        int sreg = 0; float e = 0.f;
        if (l5 < cnt) {
            sreg = csr_src[base + l5];
            float v = a_s[(long)sreg * 2 + h] + adh;
            v = (v > 0.f) ? v : NEG * v;
            e = expf(v);
            den += e;
        }
        int jmax = (cnt + 1) >> 1;
        for (int j = 0; j < jmax; ++j) {
            int m = 2 * j + h;
            int s = __shfl(sreg, m);
            float w0 = __shfl(e, m);
            float w1 = __shfl(e, 32 | m);
            float4 v = *(const float4*)(x + (long)s * IN_F + l5 * 4);
            a0[0] = fmaf(w0, v.x, a0[0]); a0[1] = fmaf(w0, v.y, a0[1]);
            a0[2] = fmaf(w0, v.z, a0[2]); a0[3] = fmaf(w0, v.w, a0[3]);
            a1[0] = fmaf(w1, v.x, a1[0]); a1[1] = fmaf(w1, v.y, a1[1]);
            a1[2] = fmaf(w1, v.z, a1[2]); a1[3] = fmaf(w1, v.w, a1[3]);
        }
    }
    #pragma unroll
    for (int o = 16; o > 0; o >>= 1) den += __shfl_xor(den, o);
    #pragma unroll
    for (int p = 0; p < 4; ++p) {
        a0[p] += __shfl_xor(a0[p], 32);
        a1[p] += __shfl_xor(a1[p], 32);
    }
    float inv = 1.0f / (den + 1e-16f);
    float* acch = (h == 0) ? a0 : a1;
    float4 o4 = {acch[0] * inv, acch[1] * inv, acch[2] * inv, acch[3] * inv};
    *(float4*)(G + (long)d * F1 + h * 128 + l5 * 4) = o4;
}

// ------- layer-2 aggregation: 4 edges in flight, float4 loads ---------------
__global__ __launch_bounds__(256) void agg2_csr(
    const int* __restrict__ rowptr, const int* __restrict__ csr_src,
    const float* __restrict__ a_s, const float* __restrict__ a_d,  // [N]
    const float* __restrict__ xh2, const float* __restrict__ b2,
    float* __restrict__ out2b, int N)
{
    int wave = threadIdx.x >> 6, lane = threadIdx.x & 63;
    int d = blockIdx.x * 4 + wave;
    if (d >= N) return;
    int row = rowptr[d], end = rowptr[d + 1];
    float adv = a_d[d];
    int g = lane >> 4, q = lane & 15;
    float acc[4] = {0,0,0,0};
    float den = 0.f;
    for (int base = row; base < end; base += 64) {
        int cnt = min(64, end - base);
        float ev = 0.f; int sreg = 0;
        if (lane < cnt) {
            sreg = csr_src[base + lane];
            float v = a_s[sreg] + adv; v = (v > 0.f) ? v : NEG * v;
            ev = expf(v);
            den += ev;
        }
        int jmax = (cnt + 3) >> 2;
        for (int j = 0; j < jmax; ++j) {
            int m = 4 * j + g;
            int s = __shfl(sreg, m);
            float w = __shfl(ev, m);
            float4 v = *(const float4*)(xh2 + (long)s * F2 + q * 4);
            acc[0] = fmaf(w, v.x, acc[0]); acc[1] = fmaf(w, v.y, acc[1]);
            acc[2] = fmaf(w, v.z, acc[2]); acc[3] = fmaf(w, v.w, acc[3]);
        }
    }
    #pragma unroll
    for (int o = 32; o > 0; o >>= 1) den += __shfl_xor(den, o);
    #pragma unroll
    for (int p = 0; p < 4; ++p) {
        acc[p] += __shfl_xor(acc[p], 16);
        acc[p] += __shfl_xor(acc[p], 32);
    }
    if (g == 0) {
        float inv = 1.0f / (den + 1e-16f);
        float4 bb = *(const float4*)&b2[q * 4];
        float4 o4 = {acc[0] * inv + bb.x, acc[1] * inv + bb.y,
                     acc[2] * inv + bb.z, acc[3] * inv + bb.w};
        *(float4*)(out2b + (long)d * F2 + q * 4) = o4;
    }
}

// ---------------- decode: 16 lanes/edge, float4 loads ------------------------
__global__ __launch_bounds__(256) void decode_k(
    const int* __restrict__ e0, const int* __restrict__ e1,
    const float* __restrict__ z2b, float* __restrict__ out, int E)
{
    int q = threadIdx.x & 15;
    long e = (long)blockIdx.x * 16 + (threadIdx.x >> 4);
    if (e >= E) return;
    int a = e0[e], b = e1[e];
    float4 va = *(const float4*)(z2b + (long)a * F2 + q * 4);
    float4 vb = *(const float4*)(z2b + (long)b * F2 + q * 4);
    float p = va.x * vb.x + va.y * vb.y + va.z * vb.z + va.w * vb.w;
    #pragma unroll
    for (int o = 1; o < 16; o <<= 1) p += __shfl_xor(p, o);
    if (q == 0) out[e] = p;
}

extern "C" void kernel_launch(void* const* d_in, const int* in_sizes, int n_in,
                              void* d_out, int out_size, void* d_ws, size_t ws_size,
                              hipStream_t stream) {
    const float* x   = (const float*)d_in[0];
    const int*   ei  = (const int*)d_in[1];
    const float* W1  = (const float*)d_in[2];
    const float* as1 = (const float*)d_in[3];
    const float* ad1 = (const float*)d_in[4];
    const float* b1  = (const float*)d_in[5];
    const float* W2  = (const float*)d_in[6];
    const float* as2 = (const float*)d_in[7];
    const float* ad2 = (const float*)d_in[8];
    const float* b2  = (const float*)d_in[9];

    int N  = in_sizes[0] / IN_F;   // 50000
    int E  = in_sizes[1] / 2;      // 600000
    int Ep = E + N;
    const int* ei_src = ei;
    const int* ei_dst = ei + E;

    float* ws = (float*)d_ws;
    size_t off = 0;
    auto alloc = [&](size_t n) { float* p = ws + off; off += (n + 63) & ~(size_t)63; return p; };

    float* G      = alloc((size_t)N * F1);
    float* z1     = alloc((size_t)N * F1);
    float* xh2    = alloc((size_t)N * F2);
    float* out2b  = alloc((size_t)N * F2);
    float* a_src1 = alloc((size_t)N * H1);
    float* a_dst1 = alloc((size_t)N * H1);
    float* a_src2 = alloc(N);
    float* a_dst2 = alloc(N);
    float* UV4    = alloc(IN_F * 4);
    int* rowptr   = (int*)alloc(N + 64);
    int* csr_src  = (int*)alloc(Ep);
    int* deg      = (int*)alloc(N);
    int* cursor   = (int*)alloc(N);
    hipMemsetAsync(deg, 0, ((size_t)(cursor + N) - (size_t)deg), stream);

    // CSR build
    hist_k<<<(Ep + 255) / 256, 256, 0, stream>>>(ei_dst, deg, E, Ep);
    scan_k<<<1, 1024, 0, stream>>>(deg, rowptr, N);
    scatter_k<<<(Ep + 255) / 256, 256, 0, stream>>>(ei_src, ei_dst, rowptr, cursor, csr_src, E, Ep);

    int mt = (N + 127) / 128;
    // layer 1: attention scalars from x directly, aggregate x, then GEMM
    uv_k<<<1, 256, 0, stream>>>(W1, as1, ad1, UV4);
    att1v_k<<<(N + 3) / 4, 256, 0, stream>>>(x, UV4, a_src1, a_dst1, N);
    agg1x<<<(N + 3) / 4, 256, 0, stream>>>(rowptr, csr_src, a_src1, a_dst1, x, G, N);
    // z1[:, by*64..] = G[:, (by>>1)*128..] @ W1[:, by*64..]
    gemm_tiled<IN_F, F1, F1, F1, false, false, true><<<dim3(mt, 4), 256, 0, stream>>>(
        G, nullptr, W1, z1, nullptr, nullptr, nullptr, nullptr, N);

    // layer 2
    gemm_tiled<F1, F1, F2, F2, true, true, false><<<dim3(mt, 1), 256, 0, stream>>>(
        z1, b1, W2, xh2, as2, ad2, a_src2, a_dst2, N);
    agg2_csr<<<(N + 3) / 4, 256, 0, stream>>>(rowptr, csr_src, a_src2, a_dst2, xh2, b2, out2b, N);

    // decode
    decode_k<<<(E + 15) / 16, 256, 0, stream>>>(ei_src, ei_dst, out2b, (float*)d_out, E);
}

// Round 7
// 376.036 us; speedup vs baseline: 7.3652x; 1.0850x over previous
//
#include <hip/hip_runtime.h>
#include <math.h>

#define IN_F 128
#define F1 256   // H1*C1
#define H1 2
#define F2 64
#define NEG 0.2f

// ---------------- tiled fp32 GEMM: TM x 64 tile, SK=32 K-chunks --------------
// TM = RPT*16 rows (RPT rows/thread), 64 cols (4/thread). block(256).
// LDS: As[32][TM] + Ws[32][64] = 24 KB (RPT=8) / 16 KB (RPT=4) -> 6-8 blk/CU.
// HEADOFF: A col offset = (blockIdx.y>>1)*KTOT. RELU: stage act(A+bias).
// ATT_EP: fused a_src/a_dst row dots (single col-tile, LDC==64).
template<int KTOT, int RPT, int LDA, int LDW, int LDC, bool RELU, bool ATT_EP, bool HEADOFF>
__global__ __launch_bounds__(256) void gemm_tiled(
    const float* __restrict__ A, const float* __restrict__ bias,
    const float* __restrict__ W, float* __restrict__ C,
    const float* __restrict__ att_s, const float* __restrict__ att_d,
    float* __restrict__ a_src, float* __restrict__ a_dst, int M)
{
    constexpr int TM = RPT * 16;
    constexpr int PARTS = 256 / TM;     // threads per row for A staging
    constexpr int F4PT = 8 / PARTS;     // float4 per thread per chunk
    __shared__ float As[32][TM];        // [k][row]
    __shared__ float Ws[32][64];        // [k][col]
    int t = threadIdx.x;
    int tx = t & 15, ty = t >> 4;
    int m0 = blockIdx.x * TM;
    int n0 = blockIdx.y * 64;
    long aoff = HEADOFF ? (long)(blockIdx.y >> 1) * KTOT : 0;
    float acc[RPT][4];
    #pragma unroll
    for (int i = 0; i < RPT; ++i)
        #pragma unroll
        for (int j = 0; j < 4; ++j) acc[i][j] = 0.f;

    int ar = t & (TM - 1);
    int apart = t / TM;
    int arow = m0 + ar; if (arow >= M) arow = M - 1;
    int kw = t >> 4;

    for (int kc = 0; kc < KTOT; kc += 32) {
        // stage A transposed: As[k][r]
        const float* ap = A + (long)arow * LDA + aoff + kc + apart * F4PT * 4;
        #pragma unroll
        for (int p = 0; p < F4PT; ++p) {
            int kk = apart * F4PT * 4 + p * 4;
            float4 v = *(const float4*)(ap + p * 4);
            if (RELU) {
                float4 bb = *(const float4*)&bias[kc + kk];
                v.x = fmaxf(v.x + bb.x, 0.f);
                v.y = fmaxf(v.y + bb.y, 0.f);
                v.z = fmaxf(v.z + bb.z, 0.f);
                v.w = fmaxf(v.w + bb.w, 0.f);
            }
            As[kk + 0][ar] = v.x;
            As[kk + 1][ar] = v.y;
            As[kk + 2][ar] = v.z;
            As[kk + 3][ar] = v.w;
        }
        // stage W: Ws[k][c], two coalesced float4 per thread
        *(float4*)&Ws[kw][(t & 15) * 4] =
            *(const float4*)&W[(long)(kc + kw) * LDW + n0 + (t & 15) * 4];
        *(float4*)&Ws[kw + 16][(t & 15) * 4] =
            *(const float4*)&W[(long)(kc + kw + 16) * LDW + n0 + (t & 15) * 4];
        __syncthreads();
        #pragma unroll 4
        for (int k = 0; k < 32; ++k) {
            float4 w4 = *(const float4*)&Ws[k][tx * 4];
            float wv[4] = {w4.x, w4.y, w4.z, w4.w};
            #pragma unroll
            for (int i2 = 0; i2 < RPT / 4; ++i2) {
                float4 a4 = *(const float4*)&As[k][ty * RPT + i2 * 4];
                float av[4] = {a4.x, a4.y, a4.z, a4.w};
                #pragma unroll
                for (int i = 0; i < 4; ++i)
                    #pragma unroll
                    for (int j = 0; j < 4; ++j)
                        acc[i2 * 4 + i][j] = fmaf(av[i], wv[j], acc[i2 * 4 + i][j]);
            }
        }
        __syncthreads();
    }
    #pragma unroll
    for (int i = 0; i < RPT; ++i) {
        int row = m0 + ty * RPT + i;
        if (row < M) {
            float4 o4 = {acc[i][0], acc[i][1], acc[i][2], acc[i][3]};
            *(float4*)&C[(long)row * LDC + n0 + tx * 4] = o4;
        }
    }
    if (ATT_EP) {
        float4 as4 = *(const float4*)&att_s[tx * 4];
        float4 ad4 = *(const float4*)&att_d[tx * 4];
        #pragma unroll
        for (int i = 0; i < RPT; ++i) {
            float ps = acc[i][0] * as4.x + acc[i][1] * as4.y +
                       acc[i][2] * as4.z + acc[i][3] * as4.w;
            float pd = acc[i][0] * ad4.x + acc[i][1] * ad4.y +
                       acc[i][2] * ad4.z + acc[i][3] * ad4.w;
            #pragma unroll
            for (int o = 1; o < 16; o <<= 1) {
                ps += __shfl_xor(ps, o);
                pd += __shfl_xor(pd, o);
            }
            int row = m0 + ty * RPT + i;
            if (tx == 0 && row < M) { a_src[row] = ps; a_dst[row] = pd; }
        }
    }
}

// ------- UV precompute: UV4[k] = {U[k,0],U[k,1],V[k,0],V[k,1]} ---------------
__global__ void uv_k(const float* __restrict__ W1, const float* __restrict__ as1,
                     const float* __restrict__ ad1, float* __restrict__ UV4)
{
    int t = threadIdx.x;
    int k = t >> 1, h = t & 1;
    const float* wrow = W1 + (long)k * F1 + h * 128;
    const float* sa = as1 + h * 128;
    const float* da = ad1 + h * 128;
    float u = 0.f, v = 0.f;
    for (int c = 0; c < 128; ++c) {
        float w = wrow[c];
        u = fmaf(w, sa[c], u);
        v = fmaf(w, da[c], v);
    }
    UV4[k * 4 + h] = u;
    UV4[k * 4 + 2 + h] = v;
}

// ------- layer-1 attention scalars -------------------------------------------
__global__ __launch_bounds__(256) void att1v_k(
    const float* __restrict__ x, const float* __restrict__ UV4,
    float* __restrict__ a_src, float* __restrict__ a_dst, int N)
{
    int wave = threadIdx.x >> 6, lane = threadIdx.x & 63;
    int n = blockIdx.x * 4 + wave;
    if (n >= N) return;
    float2 xv = ((const float2*)(x + (long)n * IN_F))[lane];
    float4 u0 = ((const float4*)UV4)[2 * lane];
    float4 u1 = ((const float4*)UV4)[2 * lane + 1];
    float p0 = xv.x * u0.x + xv.y * u1.x;
    float p1 = xv.x * u0.y + xv.y * u1.y;
    float p2 = xv.x * u0.z + xv.y * u1.z;
    float p3 = xv.x * u0.w + xv.y * u1.w;
    #pragma unroll
    for (int o = 32; o > 0; o >>= 1) {
        p0 += __shfl_xor(p0, o); p1 += __shfl_xor(p1, o);
        p2 += __shfl_xor(p2, o); p3 += __shfl_xor(p3, o);
    }
    if (lane == 0) {
        a_src[(long)n * 2 + 0] = p0; a_src[(long)n * 2 + 1] = p1;
        a_dst[(long)n * 2 + 0] = p2; a_dst[(long)n * 2 + 1] = p3;
    }
}

// ---------------- CSR build: histogram -> 3-phase scan -> scatter ------------
__global__ void hist_k(const int* __restrict__ ei_d, int* __restrict__ deg, int E, int Ep)
{
    int i = blockIdx.x * blockDim.x + threadIdx.x;
    if (i >= Ep) return;
    int d = (i < E) ? ei_d[i] : (i - E);
    atomicAdd(&deg[d], 1);
}

// phase A: per-1024-block exclusive scan; write block total to bsum[b]
__global__ __launch_bounds__(1024) void scanA_k(const int* __restrict__ deg,
                                                int* __restrict__ rowptr,
                                                int* __restrict__ bsum, int N)
{
    __shared__ int wsum[16];
    int t = threadIdx.x, lane = t & 63, w = t >> 6;
    int i = blockIdx.x * 1024 + t;
    int v = (i < N) ? deg[i] : 0;
    int incl = v;
    #pragma unroll
    for (int o = 1; o < 64; o <<= 1) {
        int nb = __shfl_up(incl, o);
        if (lane >= o) incl += nb;
    }
    if (lane == 63) wsum[w] = incl;
    __syncthreads();
    if (w == 0 && lane < 16) {
        int x = wsum[lane];
        #pragma unroll
        for (int o = 1; o < 16; o <<= 1) {
            int nb = __shfl_up(x, o);
            if (lane >= o) x += nb;
        }
        wsum[lane] = x;
    }
    __syncthreads();
    int woff = (w == 0) ? 0 : wsum[w - 1];
    if (i < N) rowptr[i] = woff + incl - v;
    if (t == 1023) bsum[blockIdx.x] = woff + incl;
}

// phase B: one wave scans the <=64 block sums; writes exclusive sums + total
__global__ void scanB_k(int* __restrict__ bsum, int* __restrict__ bex,
                        int* __restrict__ rowptr, int NBLK, int N)
{
    int lane = threadIdx.x & 63;
    int v = (lane < NBLK) ? bsum[lane] : 0;
    int incl = v;
    #pragma unroll
    for (int o = 1; o < 64; o <<= 1) {
        int nb = __shfl_up(incl, o);
        if (lane >= o) incl += nb;
    }
    if (lane < NBLK) bex[lane] = incl - v;
    if (lane == NBLK - 1) rowptr[N] = incl;
}

// phase C: add block offsets
__global__ __launch_bounds__(1024) void scanC_k(int* __restrict__ rowptr,
                                                const int* __restrict__ bex, int N)
{
    int i = blockIdx.x * 1024 + threadIdx.x;
    if (i < N) rowptr[i] += bex[blockIdx.x];
}

__global__ void scatter_k(const int* __restrict__ ei_s, const int* __restrict__ ei_d,
                          const int* __restrict__ rowptr, int* __restrict__ cursor,
                          int* __restrict__ csr_src, int E, int Ep)
{
    int i = blockIdx.x * blockDim.x + threadIdx.x;
    if (i >= Ep) return;
    int s = (i < E) ? ei_s[i] : (i - E);
    int d = (i < E) ? ei_d[i] : (i - E);
    int pos = atomicAdd(&cursor[d], 1);
    csr_src[rowptr[d] + pos] = s;
}

// ------- layer-1 aggregation in INPUT space ---------------------------------
__global__ __launch_bounds__(256) void agg1x(
    const int* __restrict__ rowptr, const int* __restrict__ csr_src,
    const float* __restrict__ a_s, const float* __restrict__ a_d,  // [N,2]
    const float* __restrict__ x, float* __restrict__ G, int N)
{
    int wave = threadIdx.x >> 6, lane = threadIdx.x & 63;
    int d = blockIdx.x * 4 + wave;
    if (d >= N) return;
    int row = rowptr[d], end = rowptr[d + 1];
    int h = lane >> 5, l5 = lane & 31;
    float adh = a_d[(long)d * 2 + h];
    float a0[4] = {0,0,0,0}, a1[4] = {0,0,0,0};
    float den = 0.f;
    for (int base = row; base < end; base += 32) {
        int cnt = min(32, end - base);
        int sreg = 0; float e = 0.f;
        if (l5 < cnt) {
            sreg = csr_src[base + l5];
            float v = a_s[(long)sreg * 2 + h] + adh;
            v = (v > 0.f) ? v : NEG * v;
            e = expf(v);
            den += e;
        }
        int jmax = (cnt + 1) >> 1;
        for (int j = 0; j < jmax; ++j) {
            int m = 2 * j + h;
            int s = __shfl(sreg, m);
            float w0 = __shfl(e, m);
            float w1 = __shfl(e, 32 | m);
            float4 v = *(const float4*)(x + (long)s * IN_F + l5 * 4);
            a0[0] = fmaf(w0, v.x, a0[0]); a0[1] = fmaf(w0, v.y, a0[1]);
            a0[2] = fmaf(w0, v.z, a0[2]); a0[3] = fmaf(w0, v.w, a0[3]);
            a1[0] = fmaf(w1, v.x, a1[0]); a1[1] = fmaf(w1, v.y, a1[1]);
            a1[2] = fmaf(w1, v.z, a1[2]); a1[3] = fmaf(w1, v.w, a1[3]);
        }
    }
    #pragma unroll
    for (int o = 16; o > 0; o >>= 1) den += __shfl_xor(den, o);
    #pragma unroll
    for (int p = 0; p < 4; ++p) {
        a0[p] += __shfl_xor(a0[p], 32);
        a1[p] += __shfl_xor(a1[p], 32);
    }
    float inv = 1.0f / (den + 1e-16f);
    float* acch = (h == 0) ? a0 : a1;
    float4 o4 = {acch[0] * inv, acch[1] * inv, acch[2] * inv, acch[3] * inv};
    *(float4*)(G + (long)d * F1 + h * 128 + l5 * 4) = o4;
}

// ------- layer-2 aggregation -------------------------------------------------
__global__ __launch_bounds__(256) void agg2_csr(
    const int* __restrict__ rowptr, const int* __restrict__ csr_src,
    const float* __restrict__ a_s, const float* __restrict__ a_d,  // [N]
    const float* __restrict__ xh2, const float* __restrict__ b2,
    float* __restrict__ out2b, int N)
{
    int wave = threadIdx.x >> 6, lane = threadIdx.x & 63;
    int d = blockIdx.x * 4 + wave;
    if (d >= N) return;
    int row = rowptr[d], end = rowptr[d + 1];
    float adv = a_d[d];
    int g = lane >> 4, q = lane & 15;
    float acc[4] = {0,0,0,0};
    float den = 0.f;
    for (int base = row; base < end; base += 64) {
        int cnt = min(64, end - base);
        float ev = 0.f; int sreg = 0;
        if (lane < cnt) {
            sreg = csr_src[base + lane];
            float v = a_s[sreg] + adv; v = (v > 0.f) ? v : NEG * v;
            ev = expf(v);
            den += ev;
        }
        int jmax = (cnt + 3) >> 2;
        for (int j = 0; j < jmax; ++j) {
            int m = 4 * j + g;
            int s = __shfl(sreg, m);
            float w = __shfl(ev, m);
            float4 v = *(const float4*)(xh2 + (long)s * F2 + q * 4);
            acc[0] = fmaf(w, v.x, acc[0]); acc[1] = fmaf(w, v.y, acc[1]);
            acc[2] = fmaf(w, v.z, acc[2]); acc[3] = fmaf(w, v.w, acc[3]);
        }
    }
    #pragma unroll
    for (int o = 32; o > 0; o >>= 1) den += __shfl_xor(den, o);
    #pragma unroll
    for (int p = 0; p < 4; ++p) {
        acc[p] += __shfl_xor(acc[p], 16);
        acc[p] += __shfl_xor(acc[p], 32);
    }
    if (g == 0) {
        float inv = 1.0f / (den + 1e-16f);
        float4 bb = *(const float4*)&b2[q * 4];
        float4 o4 = {acc[0] * inv + bb.x, acc[1] * inv + bb.y,
                     acc[2] * inv + bb.z, acc[3] * inv + bb.w};
        *(float4*)(out2b + (long)d * F2 + q * 4) = o4;
    }
}

// ---------------- decode: 16 lanes/edge, float4 loads ------------------------
__global__ __launch_bounds__(256) void decode_k(
    const int* __restrict__ e0, const int* __restrict__ e1,
    const float* __restrict__ z2b, float* __restrict__ out, int E)
{
    int q = threadIdx.x & 15;
    long e = (long)blockIdx.x * 16 + (threadIdx.x >> 4);
    if (e >= E) return;
    int a = e0[e], b = e1[e];
    float4 va = *(const float4*)(z2b + (long)a * F2 + q * 4);
    float4 vb = *(const float4*)(z2b + (long)b * F2 + q * 4);
    float p = va.x * vb.x + va.y * vb.y + va.z * vb.z + va.w * vb.w;
    #pragma unroll
    for (int o = 1; o < 16; o <<= 1) p += __shfl_xor(p, o);
    if (q == 0) out[e] = p;
}

extern "C" void kernel_launch(void* const* d_in, const int* in_sizes, int n_in,
                              void* d_out, int out_size, void* d_ws, size_t ws_size,
                              hipStream_t stream) {
    const float* x   = (const float*)d_in[0];
    const int*   ei  = (const int*)d_in[1];
    const float* W1  = (const float*)d_in[2];
    const float* as1 = (const float*)d_in[3];
    const float* ad1 = (const float*)d_in[4];
    const float* b1  = (const float*)d_in[5];
    const float* W2  = (const float*)d_in[6];
    const float* as2 = (const float*)d_in[7];
    const float* ad2 = (const float*)d_in[8];
    const float* b2  = (const float*)d_in[9];

    int N  = in_sizes[0] / IN_F;   // 50000
    int E  = in_sizes[1] / 2;      // 600000
    int Ep = E + N;
    const int* ei_src = ei;
    const int* ei_dst = ei + E;

    float* ws = (float*)d_ws;
    size_t off = 0;
    auto alloc = [&](size_t n) { float* p = ws + off; off += (n + 63) & ~(size_t)63; return p; };

    float* G      = alloc((size_t)N * F1);
    float* z1     = alloc((size_t)N * F1);
    float* xh2    = alloc((size_t)N * F2);
    float* out2b  = alloc((size_t)N * F2);
    float* a_src1 = alloc((size_t)N * H1);
    float* a_dst1 = alloc((size_t)N * H1);
    float* a_src2 = alloc(N);
    float* a_dst2 = alloc(N);
    float* UV4    = alloc(IN_F * 4);
    int* rowptr   = (int*)alloc(N + 64);
    int* csr_src  = (int*)alloc(Ep);
    int* bsum     = (int*)alloc(64);
    int* bex      = (int*)alloc(64);
    int* deg      = (int*)alloc(N);
    int* cursor   = (int*)alloc(N);
    hipMemsetAsync(deg, 0, ((size_t)(cursor + N) - (size_t)deg), stream);

    int NBLK = (N + 1023) / 1024;   // 49
    // CSR build
    hist_k<<<(Ep + 255) / 256, 256, 0, stream>>>(ei_dst, deg, E, Ep);
    scanA_k<<<NBLK, 1024, 0, stream>>>(deg, rowptr, bsum, N);
    scanB_k<<<1, 64, 0, stream>>>(bsum, bex, rowptr, NBLK, N);
    scanC_k<<<NBLK, 1024, 0, stream>>>(rowptr, bex, N);
    scatter_k<<<(Ep + 255) / 256, 256, 0, stream>>>(ei_src, ei_dst, rowptr, cursor, csr_src, E, Ep);

    // layer 1: attention scalars from x directly, aggregate x, then GEMM
    uv_k<<<1, 256, 0, stream>>>(W1, as1, ad1, UV4);
    att1v_k<<<(N + 3) / 4, 256, 0, stream>>>(x, UV4, a_src1, a_dst1, N);
    agg1x<<<(N + 3) / 4, 256, 0, stream>>>(rowptr, csr_src, a_src1, a_dst1, x, G, N);
    // z1[:, by*64..] = G[:, (by>>1)*128..] @ W1[:, by*64..]
    int mt1 = (N + 127) / 128;
    gemm_tiled<IN_F, 8, F1, F1, F1, false, false, true><<<dim3(mt1, 4), 256, 0, stream>>>(
        G, nullptr, W1, z1, nullptr, nullptr, nullptr, nullptr, N);

    // layer 2: 64-row tiles for grid parallelism
    int mt2 = (N + 63) / 64;
    gemm_tiled<F1, 4, F1, F2, F2, true, true, false><<<dim3(mt2, 1), 256, 0, stream>>>(
        z1, b1, W2, xh2, as2, ad2, a_src2, a_dst2, N);
    agg2_csr<<<(N + 3) / 4, 256, 0, stream>>>(rowptr, csr_src, a_src2, a_dst2, xh2, b2, out2b, N);

    // decode
    decode_k<<<(E + 15) / 16, 256, 0, stream>>>(ei_src, ei_dst, out2b, (float*)d_out, E);
}

// Round 8
// 375.861 us; speedup vs baseline: 7.3686x; 1.0005x over previous
//
#include <hip/hip_runtime.h>
#include <math.h>

#define IN_F 128
#define F1 256   // H1*C1
#define H1 2
#define F2 64
#define NEG 0.2f

// ---------------- tiled fp32 GEMM: TM x TN tile, RM x RN per thread ----------
// 256 threads: NX=TN/RN lanes on cols, NY=256/NX on rows (NY*RM==TM).
// K staged in 32-chunks. LDS = 128*TM + 128*TN bytes.
// HEADOFF: A col offset = blockIdx.y*KTOT (layer-1 per-head GEMM, TN==128).
// RELU: stage act(A+bias). ATT_EP: fused a_src/a_dst row dots (TN==64 tile).
template<int KTOT, int TM, int TN, int RM, int RN, int LDA, int LDW, int LDC,
         bool RELU, bool ATT_EP, bool HEADOFF>
__global__ __launch_bounds__(256) void gemm_tiled(
    const float* __restrict__ A, const float* __restrict__ bias,
    const float* __restrict__ W, float* __restrict__ C,
    const float* __restrict__ att_s, const float* __restrict__ att_d,
    float* __restrict__ a_src, float* __restrict__ a_dst, int M)
{
    constexpr int NX = TN / RN;
    constexpr int NY = 256 / NX;
    static_assert(NY * RM == TM, "tile mismatch");
    __shared__ float As[32][TM];
    __shared__ float Ws[32][TN];
    int t = threadIdx.x;
    int tx = t % NX, ty = t / NX;
    int m0 = blockIdx.x * TM;
    int n0 = blockIdx.y * TN;
    long aoff = HEADOFF ? (long)blockIdx.y * KTOT : 0;
    float acc[RM][RN];
    #pragma unroll
    for (int i = 0; i < RM; ++i)
        #pragma unroll
        for (int j = 0; j < RN; ++j) acc[i][j] = 0.f;

    constexpr int PARTS = 256 / TM;     // threads per A row
    constexpr int F4PT = 8 / PARTS;     // float4 per thread per chunk
    int ar = t % TM, apart = t / TM;
    int arow = m0 + ar; if (arow >= M) arow = M - 1;
    constexpr int WTPK = TN / 4;        // threads per W k-row
    constexpr int WKP = 256 / WTPK;     // k-rows per pass
    int wk0 = t / WTPK, wc = t % WTPK;

    for (int kc = 0; kc < KTOT; kc += 32) {
        // stage A transposed: As[k][r]
        const float* ap = A + (long)arow * LDA + aoff + kc + apart * (F4PT * 4);
        #pragma unroll
        for (int p = 0; p < F4PT; ++p) {
            int kk = apart * (F4PT * 4) + p * 4;
            float4 v = *(const float4*)(ap + p * 4);
            if (RELU) {
                float4 bb = *(const float4*)&bias[kc + kk];
                v.x = fmaxf(v.x + bb.x, 0.f);
                v.y = fmaxf(v.y + bb.y, 0.f);
                v.z = fmaxf(v.z + bb.z, 0.f);
                v.w = fmaxf(v.w + bb.w, 0.f);
            }
            As[kk + 0][ar] = v.x;
            As[kk + 1][ar] = v.y;
            As[kk + 2][ar] = v.z;
            As[kk + 3][ar] = v.w;
        }
        // stage W: Ws[k][c]
        #pragma unroll
        for (int p = 0; p < 32 / WKP; ++p) {
            int k = wk0 + p * WKP;
            *(float4*)&Ws[k][wc * 4] =
                *(const float4*)&W[(long)(kc + k) * LDW + n0 + wc * 4];
        }
        __syncthreads();
        #pragma unroll 4
        for (int k = 0; k < 32; ++k) {
            float av[RM], wv[RN];
            #pragma unroll
            for (int i4 = 0; i4 < RM / 4; ++i4) {
                float4 v = *(const float4*)&As[k][ty * RM + i4 * 4];
                av[i4 * 4 + 0] = v.x; av[i4 * 4 + 1] = v.y;
                av[i4 * 4 + 2] = v.z; av[i4 * 4 + 3] = v.w;
            }
            #pragma unroll
            for (int j4 = 0; j4 < RN / 4; ++j4) {
                float4 v = *(const float4*)&Ws[k][tx * RN + j4 * 4];
                wv[j4 * 4 + 0] = v.x; wv[j4 * 4 + 1] = v.y;
                wv[j4 * 4 + 2] = v.z; wv[j4 * 4 + 3] = v.w;
            }
            #pragma unroll
            for (int i = 0; i < RM; ++i)
                #pragma unroll
                for (int j = 0; j < RN; ++j)
                    acc[i][j] = fmaf(av[i], wv[j], acc[i][j]);
        }
        __syncthreads();
    }
    #pragma unroll
    for (int i = 0; i < RM; ++i) {
        int row = m0 + ty * RM + i;
        if (row < M) {
            #pragma unroll
            for (int j4 = 0; j4 < RN / 4; ++j4) {
                float4 o4 = {acc[i][j4 * 4 + 0], acc[i][j4 * 4 + 1],
                             acc[i][j4 * 4 + 2], acc[i][j4 * 4 + 3]};
                *(float4*)&C[(long)row * LDC + n0 + tx * RN + j4 * 4] = o4;
            }
        }
    }
    if (ATT_EP) {
        float asr[RN], adr[RN];
        #pragma unroll
        for (int j = 0; j < RN; ++j) {
            asr[j] = att_s[tx * RN + j];
            adr[j] = att_d[tx * RN + j];
        }
        #pragma unroll
        for (int i = 0; i < RM; ++i) {
            float ps = 0.f, pd = 0.f;
            #pragma unroll
            for (int j = 0; j < RN; ++j) {
                ps = fmaf(acc[i][j], asr[j], ps);
                pd = fmaf(acc[i][j], adr[j], pd);
            }
            #pragma unroll
            for (int o = 1; o < NX; o <<= 1) {
                ps += __shfl_xor(ps, o);
                pd += __shfl_xor(pd, o);
            }
            int row = m0 + ty * RM + i;
            if (tx == 0 && row < M) { a_src[row] = ps; a_dst[row] = pd; }
        }
    }
}

// ------- UV precompute: UV4[k] = {U[k,0],U[k,1],V[k,0],V[k,1]} ---------------
__global__ void uv_k(const float* __restrict__ W1, const float* __restrict__ as1,
                     const float* __restrict__ ad1, float* __restrict__ UV4)
{
    int t = threadIdx.x;
    int k = t >> 1, h = t & 1;
    const float* wrow = W1 + (long)k * F1 + h * 128;
    const float* sa = as1 + h * 128;
    const float* da = ad1 + h * 128;
    float u = 0.f, v = 0.f;
    for (int c = 0; c < 128; ++c) {
        float w = wrow[c];
        u = fmaf(w, sa[c], u);
        v = fmaf(w, da[c], v);
    }
    UV4[k * 4 + h] = u;
    UV4[k * 4 + 2 + h] = v;
}

// ------- layer-1 attention scalars -------------------------------------------
__global__ __launch_bounds__(256) void att1v_k(
    const float* __restrict__ x, const float* __restrict__ UV4,
    float* __restrict__ a_src, float* __restrict__ a_dst, int N)
{
    int wave = threadIdx.x >> 6, lane = threadIdx.x & 63;
    int n = blockIdx.x * 4 + wave;
    if (n >= N) return;
    float2 xv = ((const float2*)(x + (long)n * IN_F))[lane];
    float4 u0 = ((const float4*)UV4)[2 * lane];
    float4 u1 = ((const float4*)UV4)[2 * lane + 1];
    float p0 = xv.x * u0.x + xv.y * u1.x;
    float p1 = xv.x * u0.y + xv.y * u1.y;
    float p2 = xv.x * u0.z + xv.y * u1.z;
    float p3 = xv.x * u0.w + xv.y * u1.w;
    #pragma unroll
    for (int o = 32; o > 0; o >>= 1) {
        p0 += __shfl_xor(p0, o); p1 += __shfl_xor(p1, o);
        p2 += __shfl_xor(p2, o); p3 += __shfl_xor(p3, o);
    }
    if (lane == 0) {
        a_src[(long)n * 2 + 0] = p0; a_src[(long)n * 2 + 1] = p1;
        a_dst[(long)n * 2 + 0] = p2; a_dst[(long)n * 2 + 1] = p3;
    }
}

// ---------------- CSR build: histogram -> 3-phase scan -> scatter ------------
__global__ void hist_k(const int* __restrict__ ei_d, int* __restrict__ deg, int E, int Ep)
{
    int i = blockIdx.x * blockDim.x + threadIdx.x;
    if (i >= Ep) return;
    int d = (i < E) ? ei_d[i] : (i - E);
    atomicAdd(&deg[d], 1);
}

__global__ __launch_bounds__(1024) void scanA_k(const int* __restrict__ deg,
                                                int* __restrict__ rowptr,
                                                int* __restrict__ bsum, int N)
{
    __shared__ int wsum[16];
    int t = threadIdx.x, lane = t & 63, w = t >> 6;
    int i = blockIdx.x * 1024 + t;
    int v = (i < N) ? deg[i] : 0;
    int incl = v;
    #pragma unroll
    for (int o = 1; o < 64; o <<= 1) {
        int nb = __shfl_up(incl, o);
        if (lane >= o) incl += nb;
    }
    if (lane == 63) wsum[w] = incl;
    __syncthreads();
    if (w == 0 && lane < 16) {
        int x = wsum[lane];
        #pragma unroll
        for (int o = 1; o < 16; o <<= 1) {
            int nb = __shfl_up(x, o);
            if (lane >= o) x += nb;
        }
        wsum[lane] = x;
    }
    __syncthreads();
    int woff = (w == 0) ? 0 : wsum[w - 1];
    if (i < N) rowptr[i] = woff + incl - v;
    if (t == 1023) bsum[blockIdx.x] = woff + incl;
}

__global__ void scanB_k(int* __restrict__ bsum, int* __restrict__ bex,
                        int* __restrict__ rowptr, int NBLK, int N)
{
    int lane = threadIdx.x & 63;
    int v = (lane < NBLK) ? bsum[lane] : 0;
    int incl = v;
    #pragma unroll
    for (int o = 1; o < 64; o <<= 1) {
        int nb = __shfl_up(incl, o);
        if (lane >= o) incl += nb;
    }
    if (lane < NBLK) bex[lane] = incl - v;
    if (lane == NBLK - 1) rowptr[N] = incl;
}

__global__ __launch_bounds__(1024) void scanC_k(int* __restrict__ rowptr,
                                                const int* __restrict__ bex, int N)
{
    int i = blockIdx.x * 1024 + threadIdx.x;
    if (i < N) rowptr[i] += bex[blockIdx.x];
}

__global__ void scatter_k(const int* __restrict__ ei_s, const int* __restrict__ ei_d,
                          const int* __restrict__ rowptr, int* __restrict__ cursor,
                          int* __restrict__ csr_src, int E, int Ep)
{
    int i = blockIdx.x * blockDim.x + threadIdx.x;
    if (i >= Ep) return;
    int s = (i < E) ? ei_s[i] : (i - E);
    int d = (i < E) ? ei_d[i] : (i - E);
    int pos = atomicAdd(&cursor[d], 1);
    csr_src[rowptr[d] + pos] = s;
}

// ------- layer-1 aggregation in INPUT space ---------------------------------
__global__ __launch_bounds__(256) void agg1x(
    const int* __restrict__ rowptr, const int* __restrict__ csr_src,
    const float* __restrict__ a_s, const float* __restrict__ a_d,  // [N,2]
    const float* __restrict__ x, float* __restrict__ G, int N)
{
    int wave = threadIdx.x >> 6, lane = threadIdx.x & 63;
    int d = blockIdx.x * 4 + wave;
    if (d >= N) return;
    int row = rowptr[d], end = rowptr[d + 1];
    int h = lane >> 5, l5 = lane & 31;
    float adh = a_d[(long)d * 2 + h];
    float a0[4] = {0,0,0,0}, a1[4] = {0,0,0,0};
    float den = 0.f;
    for (int base = row; base < end; base += 32) {
        int cnt = min(32, end - base);
        int sreg = 0; float e = 0.f;
        if (l5 < cnt) {
            sreg = csr_src[base + l5];
            float v = a_s[(long)sreg * 2 + h] + adh;
            v = (v > 0.f) ? v : NEG * v;
            e = expf(v);
            den += e;
        }
        int jmax = (cnt + 1) >> 1;
        for (int j = 0; j < jmax; ++j) {
            int m = 2 * j + h;
            int s = __shfl(sreg, m);
            float w0 = __shfl(e, m);
            float w1 = __shfl(e, 32 | m);
            float4 v = *(const float4*)(x + (long)s * IN_F + l5 * 4);
            a0[0] = fmaf(w0, v.x, a0[0]); a0[1] = fmaf(w0, v.y, a0[1]);
            a0[2] = fmaf(w0, v.z, a0[2]); a0[3] = fmaf(w0, v.w, a0[3]);
            a1[0] = fmaf(w1, v.x, a1[0]); a1[1] = fmaf(w1, v.y, a1[1]);
            a1[2] = fmaf(w1, v.z, a1[2]); a1[3] = fmaf(w1, v.w, a1[3]);
        }
    }
    #pragma unroll
    for (int o = 16; o > 0; o >>= 1) den += __shfl_xor(den, o);
    #pragma unroll
    for (int p = 0; p < 4; ++p) {
        a0[p] += __shfl_xor(a0[p], 32);
        a1[p] += __shfl_xor(a1[p], 32);
    }
    float inv = 1.0f / (den + 1e-16f);
    float* acch = (h == 0) ? a0 : a1;
    float4 o4 = {acch[0] * inv, acch[1] * inv, acch[2] * inv, acch[3] * inv};
    *(float4*)(G + (long)d * F1 + h * 128 + l5 * 4) = o4;
}

// ------- layer-2 aggregation -------------------------------------------------
__global__ __launch_bounds__(256) void agg2_csr(
    const int* __restrict__ rowptr, const int* __restrict__ csr_src,
    const float* __restrict__ a_s, const float* __restrict__ a_d,  // [N]
    const float* __restrict__ xh2, const float* __restrict__ b2,
    float* __restrict__ out2b, int N)
{
    int wave = threadIdx.x >> 6, lane = threadIdx.x & 63;
    int d = blockIdx.x * 4 + wave;
    if (d >= N) return;
    int row = rowptr[d], end = rowptr[d + 1];
    float adv = a_d[d];
    int g = lane >> 4, q = lane & 15;
    float acc[4] = {0,0,0,0};
    float den = 0.f;
    for (int base = row; base < end; base += 64) {
        int cnt = min(64, end - base);
        float ev = 0.f; int sreg = 0;
        if (lane < cnt) {
            sreg = csr_src[base + lane];
            float v = a_s[sreg] + adv; v = (v > 0.f) ? v : NEG * v;
            ev = expf(v);
            den += ev;
        }
        int jmax = (cnt + 3) >> 2;
        for (int j = 0; j < jmax; ++j) {
            int m = 4 * j + g;
            int s = __shfl(sreg, m);
            float w = __shfl(ev, m);
            float4 v = *(const float4*)(xh2 + (long)s * F2 + q * 4);
            acc[0] = fmaf(w, v.x, acc[0]); acc[1] = fmaf(w, v.y, acc[1]);
            acc[2] = fmaf(w, v.z, acc[2]); acc[3] = fmaf(w, v.w, acc[3]);
        }
    }
    #pragma unroll
    for (int o = 32; o > 0; o >>= 1) den += __shfl_xor(den, o);
    #pragma unroll
    for (int p = 0; p < 4; ++p) {
        acc[p] += __shfl_xor(acc[p], 16);
        acc[p] += __shfl_xor(acc[p], 32);
    }
    if (g == 0) {
        float inv = 1.0f / (den + 1e-16f);
        float4 bb = *(const float4*)&b2[q * 4];
        float4 o4 = {acc[0] * inv + bb.x, acc[1] * inv + bb.y,
                     acc[2] * inv + bb.z, acc[3] * inv + bb.w};
        *(float4*)(out2b + (long)d * F2 + q * 4) = o4;
    }
}

// ---------------- decode: 16 lanes/edge, float4 loads ------------------------
__global__ __launch_bounds__(256) void decode_k(
    const int* __restrict__ e0, const int* __restrict__ e1,
    const float* __restrict__ z2b, float* __restrict__ out, int E)
{
    int q = threadIdx.x & 15;
    long e = (long)blockIdx.x * 16 + (threadIdx.x >> 4);
    if (e >= E) return;
    int a = e0[e], b = e1[e];
    float4 va = *(const float4*)(z2b + (long)a * F2 + q * 4);
    float4 vb = *(const float4*)(z2b + (long)b * F2 + q * 4);
    float p = va.x * vb.x + va.y * vb.y + va.z * vb.z + va.w * vb.w;
    #pragma unroll
    for (int o = 1; o < 16; o <<= 1) p += __shfl_xor(p, o);
    if (q == 0) out[e] = p;
}

extern "C" void kernel_launch(void* const* d_in, const int* in_sizes, int n_in,
                              void* d_out, int out_size, void* d_ws, size_t ws_size,
                              hipStream_t stream) {
    const float* x   = (const float*)d_in[0];
    const int*   ei  = (const int*)d_in[1];
    const float* W1  = (const float*)d_in[2];
    const float* as1 = (const float*)d_in[3];
    const float* ad1 = (const float*)d_in[4];
    const float* b1  = (const float*)d_in[5];
    const float* W2  = (const float*)d_in[6];
    const float* as2 = (const float*)d_in[7];
    const float* ad2 = (const float*)d_in[8];
    const float* b2  = (const float*)d_in[9];

    int N  = in_sizes[0] / IN_F;   // 50000
    int E  = in_sizes[1] / 2;      // 600000
    int Ep = E + N;
    const int* ei_src = ei;
    const int* ei_dst = ei + E;

    float* ws = (float*)d_ws;
    size_t off = 0;
    auto alloc = [&](size_t n) { float* p = ws + off; off += (n + 63) & ~(size_t)63; return p; };

    float* G      = alloc((size_t)N * F1);
    float* z1     = alloc((size_t)N * F1);
    float* xh2    = alloc((size_t)N * F2);
    float* out2b  = alloc((size_t)N * F2);
    float* a_src1 = alloc((size_t)N * H1);
    float* a_dst1 = alloc((size_t)N * H1);
    float* a_src2 = alloc(N);
    float* a_dst2 = alloc(N);
    float* UV4    = alloc(IN_F * 4);
    int* rowptr   = (int*)alloc(N + 64);
    int* csr_src  = (int*)alloc(Ep);
    int* bsum     = (int*)alloc(64);
    int* bex      = (int*)alloc(64);
    int* deg      = (int*)alloc(N);
    int* cursor   = (int*)alloc(N);
    hipMemsetAsync(deg, 0, ((size_t)(cursor + N) - (size_t)deg), stream);

    int NBLK = (N + 1023) / 1024;   // 49
    // CSR build
    hist_k<<<(Ep + 255) / 256, 256, 0, stream>>>(ei_dst, deg, E, Ep);
    scanA_k<<<NBLK, 1024, 0, stream>>>(deg, rowptr, bsum, N);
    scanB_k<<<1, 64, 0, stream>>>(bsum, bex, rowptr, NBLK, N);
    scanC_k<<<NBLK, 1024, 0, stream>>>(rowptr, bex, N);
    scatter_k<<<(Ep + 255) / 256, 256, 0, stream>>>(ei_src, ei_dst, rowptr, cursor, csr_src, E, Ep);

    // layer 1: attention scalars from x directly, aggregate x, then GEMM
    uv_k<<<1, 256, 0, stream>>>(W1, as1, ad1, UV4);
    att1v_k<<<(N + 3) / 4, 256, 0, stream>>>(x, UV4, a_src1, a_dst1, N);
    agg1x<<<(N + 3) / 4, 256, 0, stream>>>(rowptr, csr_src, a_src1, a_dst1, x, G, N);
    // z1[:, h*128..] = G[:, h*128..] @ W1[:, h*128..], h = blockIdx.y
    int mt1 = (N + 127) / 128;
    gemm_tiled<IN_F, 128, 128, 8, 8, F1, F1, F1, false, false, true>
        <<<dim3(mt1, 2), 256, 0, stream>>>(
        G, nullptr, W1, z1, nullptr, nullptr, nullptr, nullptr, N);

    // layer 2
    gemm_tiled<F1, 128, 64, 4, 8, F1, F2, F2, true, true, false>
        <<<dim3(mt1, 1), 256, 0, stream>>>(
        z1, b1, W2, xh2, as2, ad2, a_src2, a_dst2, N);
    agg2_csr<<<(N + 3) / 4, 256, 0, stream>>>(rowptr, csr_src, a_src2, a_dst2, xh2, b2, out2b, N);

    // decode
    decode_k<<<(E + 15) / 16, 256, 0, stream>>>(ei_src, ei_dst, out2b, (float*)d_out, E);
}